// Round 3
// baseline (3880.574 us; speedup 1.0000x reference)
//
#include <hip/hip_runtime.h>
#include <cstdint>
#include <cstddef>

typedef float    float4v __attribute__((ext_vector_type(4)));
typedef _Float16 f16x4   __attribute__((ext_vector_type(4)));
typedef _Float16 f16x8   __attribute__((ext_vector_type(8)));
typedef unsigned long long u64;

#define DI __device__ __forceinline__

static const int Bsz = 64, Tlen = 2048, Hd = 128, G4 = 512;  // 4H=512
static const int Mrows = Bsz * Tlen;                          // 131072
static const int HSTR = 144;   // H row stride (f16): 0 bank conflicts, validated R7

DI float sigf_fast(float x) {
    float e = __builtin_amdgcn_exp2f(-1.442695041f * x);
    return __builtin_amdgcn_rcpf(1.f + e);
}
DI float tanhf_fast(float x) {
    float e = __builtin_amdgcn_exp2f(-2.885390082f * x);
    return 2.f * __builtin_amdgcn_rcpf(1.f + e) - 1.f;
}

// LDS-only barrier: no vmcnt drain (validated R5, -24%).
DI void lds_barrier() {
    asm volatile("s_waitcnt lgkmcnt(0)\n\ts_barrier" ::: "memory");
}

// Pin a 128-bit fragment in VGPRs: forbids rematerialization (per-step HBM
// reload of weights). Validated R8 (FETCH 66.6GB -> 66.6MB).
DI void pin(f16x8& v) {
    float4v t = __builtin_bit_cast(float4v, v);
    asm volatile("" : "+v"(t));
    v = __builtin_bit_cast(f16x8, t);
}

// load 8 consecutive f32, convert to f16x8
DI f16x8 cvt8(const float* p) {
    float4v u = *(const float4v*)p;
    float4v w = *(const float4v*)(p + 4);
    f16x8 o;
    o[0] = (_Float16)u[0]; o[1] = (_Float16)u[1]; o[2] = (_Float16)u[2]; o[3] = (_Float16)u[3];
    o[4] = (_Float16)w[0]; o[5] = (_Float16)w[1]; o[6] = (_Float16)w[2]; o[7] = (_Float16)w[3];
    return o;
}

// ---------------------------------------------------------------------------
// GEMM: C[M,N] = A[M,128] @ Wsel^T (+bias). MFMA f32_16x16x32_f16.
// PERM: col n pulls W row ((n&3)*128 + (n>>2)) -> XP gate-interleaved (4j+q).
// Validated R4-R7.
// ---------------------------------------------------------------------------
template <bool A_F16, bool PERM, bool OUT_F32>
__global__ __launch_bounds__(256) void gemm_k128(
    const void* __restrict__ Av, const float* __restrict__ W,
    const float* __restrict__ bias, void* __restrict__ Cout, int M, int N)
{
    const int lane = threadIdx.x & 63, wave = threadIdx.x >> 6;
    const int m0 = blockIdx.y * 64 + wave * 16;
    const int n0 = blockIdx.x * 64;
    const int r15 = lane & 15, kg = lane >> 4;

    f16x8 a[4];
    if (A_F16) {
        const f16x8* Ar = (const f16x8*)((const _Float16*)Av + (size_t)(m0 + r15) * 128);
#pragma unroll
        for (int kt = 0; kt < 4; kt++) a[kt] = Ar[kt * 4 + kg];
    } else {
        const float* Ar = (const float*)Av + (size_t)(m0 + r15) * 128;
#pragma unroll
        for (int kt = 0; kt < 4; kt++) a[kt] = cvt8(Ar + kt * 32 + kg * 8);
    }

    f16x8 bfrg[4][4];
#pragma unroll
    for (int nt = 0; nt < 4; nt++) {
        int n = n0 + nt * 16 + r15;
        int wrow = PERM ? ((n & 3) * 128 + (n >> 2)) : n;
        const float* Wr = W + (size_t)wrow * 128;
#pragma unroll
        for (int kt = 0; kt < 4; kt++) bfrg[nt][kt] = cvt8(Wr + kt * 32 + kg * 8);
    }

    float4v acc[4] = {};
#pragma unroll
    for (int kt = 0; kt < 4; kt++)
#pragma unroll
        for (int nt = 0; nt < 4; nt++)
            acc[nt] = __builtin_amdgcn_mfma_f32_16x16x32_f16(a[kt], bfrg[nt][kt], acc[nt], 0, 0, 0);

#pragma unroll
    for (int nt = 0; nt < 4; nt++) {
        int n = n0 + nt * 16 + r15;
        float bv = bias ? bias[n] : 0.f;
#pragma unroll
        for (int r = 0; r < 4; r++) {
            int m = m0 + kg * 4 + r;
            float v = acc[nt][r] + bv;
            if (OUT_F32) ((float*)Cout)[(size_t)m * N + n] = v;
            else         ((_Float16*)Cout)[(size_t)m * N + n] = (_Float16)v;
        }
    }
}

// ---------------------------------------------------------------------------
// R11: fused pipeline, consumer critical-path flattened.
// R10 post-mortem: consumer step 857ns vs producer 663ns (consumer = kernel
// critical path). Two exposed costs: (a) ih-MFMA chain + frag reads sit ON
// the recurrence dependency path; (b) loader's agent u64 load vmcnt-waits at
// the ds_write near the END of the SAME step (coherence-point latency not
// covered by one compute phase). Fix:
//   - ih matvec pipelined ONE STEP AHEAD: during step t compute
//     accI(t+1) = Wih @ y(t+1) (independent of recurrence; fills idle MFMA
//     issue slots during the VALU phase). Step's path = hh chain + add.
//   - y staging TRIPLE-buffered, ds_write moved to TOP of next step: load
//     y(t+3) at step t, stage at start of t+1, frags read at t+2 -> load
//     has a full step to land; vmcnt exposure ~0.
//   - poller guarantees prog >= t+5 (one release granule earlier).
// Producer branch unchanged (validated R9/R10).
// ---------------------------------------------------------------------------
template <bool P_HAS_XP, bool P_INIT, bool C_INIT, bool C_WRITE_Y>
__global__ __launch_bounds__(512, 1) void lstm_fused2(
    const float* __restrict__ Up, const float* __restrict__ bip, const float* __restrict__ bhp,
    const _Float16* __restrict__ XPp,
    const float* __restrict__ php, const float* __restrict__ pcp,
    float* __restrict__ fhp, float* __restrict__ fcp,
    const float* __restrict__ Wc, const float* __restrict__ Uc,
    const float* __restrict__ bic, const float* __restrict__ bhc,
    const float* __restrict__ phc, const float* __restrict__ pcc,
    float* __restrict__ fhc, float* __restrict__ fcc,
    _Float16* __restrict__ PB,          // publish buffer [B,T,128] f16
    _Float16* __restrict__ Yc,          // consumer plain y out (or null)
    unsigned int* __restrict__ prog, int T)
{
    const int tid  = threadIdx.x;
    const int lane = tid & 63, w = tid >> 6;
    const int col  = lane & 15, quad = lane >> 4;
    const int b    = col & 3, s = col >> 2;
    const bool isC = blockIdx.x >= 16;
    const int p    = blockIdx.x & 15;
    const int bglob = p * 4 + b;
    const int j    = w * 16 + s * 4 + quad;

    __shared__ alignas(16) _Float16 Hl[2 * 4 * HSTR];
    __shared__ alignas(16) _Float16 Yl[3][4 * HSTR];   // y(t) triple buffer (consumer)
    const int SLAB = 4 * HSTR * 2;                     // slab stride, bytes

    unsigned int* pr = prog + p * 16;   // 64B stride: no shared-line hammering

    if (!isC) {
        // ================= producer (unchanged from R10) =================
        f16x8 af[4][4];
#pragma unroll
        for (int mt = 0; mt < 4; mt++) {
            int urow = (col & 3) * 128 + (w * 16 + mt * 4 + (col >> 2));
            const float* ur = Up + (size_t)urow * 128;
#pragma unroll
            for (int kc = 0; kc < 4; kc++) af[mt][kc] = cvt8(ur + kc * 32 + quad * 8);
        }
#pragma unroll
        for (int mt = 0; mt < 4; mt++)
#pragma unroll
            for (int kc = 0; kc < 4; kc++) pin(af[mt][kc]);

        float bq[4];
#pragma unroll
        for (int q = 0; q < 4; q++) bq[q] = bip[q * 128 + j] + bhp[q * 128 + j];

        float c = 0.f, hv = 0.f;
        if (P_INIT) {
            c  = pcp[(size_t)bglob * 128 + j];
            hv = php[(size_t)bglob * 128 + j];
        }
        Hl[b * HSTR + j] = (_Float16)hv;
        __syncthreads();

        const _Float16* xb = P_HAS_XP ? XPp + ((size_t)bglob * T) * 512 + 4 * j : nullptr;
        f16x4 xp = {};
        if (P_HAS_XP) xp = *(const f16x4*)xb;

        int cur = 0;
        for (int t = 0; t < T; t++) {
            f16x4 xpn = {};
            if (P_HAS_XP && (t + 1 < T)) xpn = *(const f16x4*)(xb + (size_t)(t + 1) * 512);

            const _Float16* Hc = Hl + cur * (4 * HSTR);
            f16x8 bf[4];
#pragma unroll
            for (int kc = 0; kc < 4; kc++)
                bf[kc] = *(const f16x8*)(Hc + b * HSTR + kc * 32 + quad * 8);

            float4v acc[4] = {};
#pragma unroll
            for (int kc = 0; kc < 4; kc++)
#pragma unroll
                for (int mt = 0; mt < 4; mt++)
                    acc[mt] = __builtin_amdgcn_mfma_f32_16x16x32_f16(af[mt][kc], bf[kc], acc[mt], 0, 0, 0);

            float4v t0 = (s & 1) ? acc[1] : acc[0];
            float4v t1 = (s & 1) ? acc[3] : acc[2];
            float4v g  = (s & 2) ? t1 : t0;

            float g0 = g[0] + bq[0], g1 = g[1] + bq[1], g2 = g[2] + bq[2], g3 = g[3] + bq[3];
            if (P_HAS_XP) { g0 += (float)xp[0]; g1 += (float)xp[1]; g2 += (float)xp[2]; g3 += (float)xp[3]; }
            float iv = sigf_fast(g0), fv = sigf_fast(g1);
            float gv = tanhf_fast(g2), ov = sigf_fast(g3);
            c  = fv * c + iv * gv;
            hv = ov * tanhf_fast(c);

            _Float16 hf = (_Float16)hv;
            Hl[(cur ^ 1) * (4 * HSTR) + b * HSTR + j] = hf;

            // publish y(t): pack (j, j+1) pairs, agent-scope u32 store
            unsigned short hs = __builtin_bit_cast(unsigned short, hf);
            unsigned int ov16 = (unsigned int)__shfl_down((int)hs, 16);   // j+1 at lane+16
            if (!(quad & 1)) {
                unsigned int pk = (unsigned int)hs | (ov16 << 16);
                __hip_atomic_store((unsigned int*)(PB + ((size_t)bglob * T + t) * 128 + j), pk,
                                   __ATOMIC_RELAXED, __HIP_MEMORY_SCOPE_AGENT);
            }

            if ((t & 7) == 7) {
                // counted release: only this step's {xp-load, y-store} may
                // remain outstanding -> all y(<=t-1) ACKed at coherence pt.
                if constexpr (P_HAS_XP) asm volatile("s_waitcnt vmcnt(2)" ::: "memory");
                else                    asm volatile("s_waitcnt vmcnt(1)" ::: "memory");
                lds_barrier();
                if (tid == 0)
                    __hip_atomic_store(pr, (unsigned int)t,   // steps 0..t-1 ready
                                       __ATOMIC_RELAXED, __HIP_MEMORY_SCOPE_AGENT);
            } else {
                lds_barrier();
            }

            xp = xpn;
            cur ^= 1;
        }

        asm volatile("s_waitcnt vmcnt(0)" ::: "memory");
        __syncthreads();
        if (tid == 0)
            __hip_atomic_store(pr, (unsigned int)T, __ATOMIC_RELAXED, __HIP_MEMORY_SCOPE_AGENT);

        fhp[(size_t)bglob * 128 + j] = hv;
        fcp[(size_t)bglob * 128 + j] = c;
    } else {
        // ======== consumer: pipelined ih, triple-buffered y staging ========
        f16x8 afI[4][4], afH[4][4];
#pragma unroll
        for (int mt = 0; mt < 4; mt++) {
            int urow = (col & 3) * 128 + (w * 16 + mt * 4 + (col >> 2));
            const float* wr = Wc + (size_t)urow * 128;
            const float* ur = Uc + (size_t)urow * 128;
#pragma unroll
            for (int kc = 0; kc < 4; kc++) {
                afI[mt][kc] = cvt8(wr + kc * 32 + quad * 8);
                afH[mt][kc] = cvt8(ur + kc * 32 + quad * 8);
            }
        }
#pragma unroll
        for (int mt = 0; mt < 4; mt++)
#pragma unroll
            for (int kc = 0; kc < 4; kc++) { pin(afI[mt][kc]); pin(afH[mt][kc]); }

        float bq[4];
#pragma unroll
        for (int q = 0; q < 4; q++) bq[q] = bic[q * 128 + j] + bhc[q * 128 + j];

        float c = 0.f, hv = 0.f;
        if (C_INIT) {
            c  = pcc[(size_t)bglob * 128 + j];
            hv = phc[(size_t)bglob * 128 + j];
        }
        Hl[b * HSTR + j] = (_Float16)hv;

        // loader mapping: tid<128 -> one unique u64 of the 1KB y row
        const bool isLoader = (tid < 128);
        const int lb = (tid >> 5) & 3, lc = tid & 31;
        const _Float16* lyb = PB + ((size_t)(p * 4 + lb) * T) * 128 + lc * 4;
        char* lws = (char*)&Yl[0][0];
        const int lo = lb * (HSTR * 2) + lc * 8;   // byte offset within a slab

        // pre-loop poller: y(0..2) pre-stage needs prog>=3; step-0 load of
        // y(3) needs prog>=4.
        unsigned int psn = 0;
        if (tid == 511) {
            unsigned int need0 = (T < 4) ? (unsigned int)T : 4u;
            psn = __hip_atomic_load(pr, __ATOMIC_RELAXED, __HIP_MEMORY_SCOPE_AGENT);
            while (psn < need0) {
                __builtin_amdgcn_s_sleep(8);
                psn = __hip_atomic_load(pr, __ATOMIC_RELAXED, __HIP_MEMORY_SCOPE_AGENT);
            }
        }
        __syncthreads();

        // pre-stage y(0), y(1), y(2) into slabs 0,1,2
        if (isLoader) {
            if (T > 0) {
                u64 v0 = __hip_atomic_load((const u64*)lyb, __ATOMIC_RELAXED, __HIP_MEMORY_SCOPE_AGENT);
                *(u64*)(lws + 0 * SLAB + lo) = v0;
            }
            if (T > 1) {
                u64 v1 = __hip_atomic_load((const u64*)(lyb + 128), __ATOMIC_RELAXED, __HIP_MEMORY_SCOPE_AGENT);
                *(u64*)(lws + 1 * SLAB + lo) = v1;
            }
            if (T > 2) {
                u64 v2 = __hip_atomic_load((const u64*)(lyb + 256), __ATOMIC_RELAXED, __HIP_MEMORY_SCOPE_AGENT);
                *(u64*)(lws + 2 * SLAB + lo) = v2;
            }
        }
        lds_barrier();

        // prime accI for step 0 from y(0)
        float4v accI[4] = {};
        if (T > 0) {
            const _Float16* Yb = (const _Float16*)(lws + 0 * SLAB);
            f16x8 yf[4];
#pragma unroll
            for (int kc = 0; kc < 4; kc++)
                yf[kc] = *(const f16x8*)(Yb + b * HSTR + kc * 32 + quad * 8);
#pragma unroll
            for (int kc = 0; kc < 4; kc++)
#pragma unroll
                for (int mt = 0; mt < 4; mt++)
                    accI[mt] = __builtin_amdgcn_mfma_f32_16x16x32_f16(afI[mt][kc], yf[kc], accI[mt], 0, 0, 0);
        }

        u64 yv = 0;
        int cur = 0;
        int sW = 2, sR = 1;   // at step t: write slab (t+2)%3, read slab (t+1)%3
        for (int t = 0; t < T; t++) {
            // stage y(t+2) (loaded during step t-1); t==0 was pre-staged.
            // Load had a FULL step to land -> vmcnt wait here is ~free.
            if (isLoader && t >= 1 && (t + 2 < T))
                *(u64*)(lws + sW * SLAB + lo) = yv;
            // issue load y(t+3): consumed at top of step t+1
            if (isLoader && (t + 3 < T))
                yv = __hip_atomic_load((const u64*)(lyb + (size_t)(t + 3) * 128),
                                       __ATOMIC_RELAXED, __HIP_MEMORY_SCOPE_AGENT);

            // ---- recurrence critical path: hh chain only ----
            const _Float16* Hc = Hl + cur * (4 * HSTR);
            f16x8 bf[4];
#pragma unroll
            for (int kc = 0; kc < 4; kc++)
                bf[kc] = *(const f16x8*)(Hc + b * HSTR + kc * 32 + quad * 8);

            float4v accH[4] = {};
#pragma unroll
            for (int kc = 0; kc < 4; kc++)
#pragma unroll
                for (int mt = 0; mt < 4; mt++)
                    accH[mt] = __builtin_amdgcn_mfma_f32_16x16x32_f16(afH[mt][kc], bf[kc], accH[mt], 0, 0, 0);

            float4v i0 = (s & 1) ? accI[1] : accI[0];
            float4v i1 = (s & 1) ? accI[3] : accI[2];
            float4v gI = (s & 2) ? i1 : i0;
            float4v h0 = (s & 1) ? accH[1] : accH[0];
            float4v h1 = (s & 1) ? accH[3] : accH[2];
            float4v gH = (s & 2) ? h1 : h0;

            float g0 = gI[0] + gH[0] + bq[0], g1 = gI[1] + gH[1] + bq[1];
            float g2 = gI[2] + gH[2] + bq[2], g3 = gI[3] + gH[3] + bq[3];
            float iv = sigf_fast(g0), fv = sigf_fast(g1);
            float gv = tanhf_fast(g2), ov = sigf_fast(g3);
            c  = fv * c + iv * gv;
            hv = ov * tanhf_fast(c);

            Hl[(cur ^ 1) * (4 * HSTR) + b * HSTR + j] = (_Float16)hv;
            if (C_WRITE_Y)
                Yc[((size_t)bglob * T + t) * 128 + j] = (_Float16)hv;

            // ---- off-path: accI(t+1) = Wih @ y(t+1), fills idle MFMA slots
            float4v accN[4] = {};
            if (t + 1 < T) {
                const _Float16* Yb = (const _Float16*)(lws + sR * SLAB);
                f16x8 yf[4];
#pragma unroll
                for (int kc = 0; kc < 4; kc++)
                    yf[kc] = *(const f16x8*)(Yb + b * HSTR + kc * 32 + quad * 8);
#pragma unroll
                for (int kc = 0; kc < 4; kc++)
#pragma unroll
                    for (int mt = 0; mt < 4; mt++)
                        accN[mt] = __builtin_amdgcn_mfma_f32_16x16x32_f16(afI[mt][kc], yf[kc], accN[mt], 0, 0, 0);
            }

            // poller: during step t, guarantee step t+1's load (y(t+4)).
            if (tid == 511 && (t + 4 < T)) {
                unsigned int need = (unsigned int)(t + 5);
                if (psn < need) {
                    psn = __hip_atomic_load(pr, __ATOMIC_RELAXED, __HIP_MEMORY_SCOPE_AGENT);
                    while (psn < need) {
                        __builtin_amdgcn_s_sleep(2);
                        psn = __hip_atomic_load(pr, __ATOMIC_RELAXED, __HIP_MEMORY_SCOPE_AGENT);
                    }
                }
            }
            lds_barrier();

#pragma unroll
            for (int mt = 0; mt < 4; mt++) accI[mt] = accN[mt];
            cur ^= 1;
            sW = (sW == 2) ? 0 : sW + 1;
            sR = (sR == 2) ? 0 : sR + 1;
        }

        fhc[(size_t)bglob * 128 + j] = hv;
        fcc[(size_t)bglob * 128 + j] = c;
    }
}

// ---------------------------------------------------------------------------
// Host side: memset + 4 stream-ordered launches.
//   ws: XP f16 [131072,512] perm (128MB) | Y f16 [131072,128] (32MB) | finals
//   prog counters: first 2KB of d_out (64B stride x 16 x 2 phases), dead
//   scratch until the final GEMM overwrites it.
// ---------------------------------------------------------------------------
extern "C" void kernel_launch(void* const* d_in, const int* in_sizes, int n_in,
                              void* d_out, int out_size, void* d_ws, size_t ws_size,
                              hipStream_t stream)
{
    const float* x    = (const float*)d_in[0];
    const float* eW0  = (const float*)d_in[1];
    const float* eU0  = (const float*)d_in[2];
    const float* eb0i = (const float*)d_in[3];
    const float* eb0h = (const float*)d_in[4];
    const float* eW1  = (const float*)d_in[5];
    const float* eU1  = (const float*)d_in[6];
    const float* eb1i = (const float*)d_in[7];
    const float* eb1h = (const float*)d_in[8];
    const float* dU0  = (const float*)d_in[10];
    const float* db0i = (const float*)d_in[11];
    const float* db0h = (const float*)d_in[12];
    const float* dW1  = (const float*)d_in[13];
    const float* dU1  = (const float*)d_in[14];
    const float* db1i = (const float*)d_in[15];
    const float* db1h = (const float*)d_in[16];
    const float* oW   = (const float*)d_in[17];
    const float* ob   = (const float*)d_in[18];

    char* ws = (char*)d_ws;
    _Float16* XP  = (_Float16*)ws;                              // 134217728 B
    _Float16* Y   = (_Float16*)(ws + 134217728);                //  33554432 B
    float*    fh0 = (float*)(ws + 167772160);
    float*    fc0 = fh0 + Bsz * Hd;
    float*    fh1 = fc0 + Bsz * Hd;
    float*    fc1 = fh1 + Bsz * Hd;

    unsigned int* progA = (unsigned int*)d_out;     // 16 x 64B
    unsigned int* progB = progA + 16 * 16;          // 16 x 64B

    dim3 blk(256);
    dim3 gXP(G4 / 64, Mrows / 64);    // (8, 2048)
    dim3 gOut(Hd / 64, Mrows / 64);   // (2, 2048)

    // zero progress counters (graph-safe, re-zeroed every replay)
    hipMemsetAsync(d_out, 0, 2048, stream);

    // 1) XP = x @ enc_Wih0^T (permuted, f16)
    gemm_k128<false, true, false><<<gXP, blk, 0, stream>>>((const void*)x, eW0, (const float*)nullptr, (void*)XP, Mrows, G4);

    // 2) encoder phase: encL0 (producer) || encL1 (consumer, dual matvec)
    lstm_fused2<true, false, false, false><<<dim3(32), dim3(512), 0, stream>>>(
        eU0, eb0i, eb0h, XP, (const float*)nullptr, (const float*)nullptr, fh0, fc0,
        eW1, eU1, eb1i, eb1h, (const float*)nullptr, (const float*)nullptr, fh1, fc1,
        Y, (_Float16*)nullptr, progA, Tlen);

    // 3) decoder phase: decL0 (producer, zero input, init enc finals) ||
    //    decL1 (consumer, init enc finals, writes final y to Y)
    lstm_fused2<false, true, true, true><<<dim3(32), dim3(512), 0, stream>>>(
        dU0, db0i, db0h, (const _Float16*)nullptr, fh0, fc0, fh0, fc0,
        dW1, dU1, db1i, db1h, fh1, fc1, fh1, fc1,
        XP /*publish scratch*/, Y, progB, Tlen);

    // 4) out = d1 @ out_W^T + out_b (f32 -> d_out, overwrites prog scratch)
    gemm_k128<true, false, true><<<gOut, blk, 0, stream>>>((const void*)Y, oW, ob, d_out, Mrows, Hd);
}

// Round 4
// 3816.919 us; speedup vs baseline: 1.0167x; 1.0167x over previous
//
#include <hip/hip_runtime.h>
#include <cstdint>
#include <cstddef>

typedef float    float4v __attribute__((ext_vector_type(4)));
typedef _Float16 f16x4   __attribute__((ext_vector_type(4)));
typedef _Float16 f16x8   __attribute__((ext_vector_type(8)));
typedef unsigned long long u64;

#define DI __device__ __forceinline__

static const int Bsz = 64, Tlen = 2048, Hd = 128, G4 = 512;  // 4H=512
static const int Mrows = Bsz * Tlen;                          // 131072
static const int HSTR = 144;   // H row stride (f16): 0 bank conflicts, validated R7

DI float sigf_fast(float x) {
    float e = __builtin_amdgcn_exp2f(-1.442695041f * x);
    return __builtin_amdgcn_rcpf(1.f + e);
}
DI float tanhf_fast(float x) {
    float e = __builtin_amdgcn_exp2f(-2.885390082f * x);
    return 2.f * __builtin_amdgcn_rcpf(1.f + e) - 1.f;
}

// LDS-only barrier: no vmcnt drain (validated R5, -24%).
DI void lds_barrier() {
    asm volatile("s_waitcnt lgkmcnt(0)\n\ts_barrier" ::: "memory");
}

// Pin a 128-bit fragment in VGPRs: forbids rematerialization (per-step HBM
// reload of weights). Validated R8 (FETCH 66.6GB -> 66.6MB).
DI void pin(f16x8& v) {
    float4v t = __builtin_bit_cast(float4v, v);
    asm volatile("" : "+v"(t));
    v = __builtin_bit_cast(f16x8, t);
}

// load 8 consecutive f32, convert to f16x8
DI f16x8 cvt8(const float* p) {
    float4v u = *(const float4v*)p;
    float4v w = *(const float4v*)(p + 4);
    f16x8 o;
    o[0] = (_Float16)u[0]; o[1] = (_Float16)u[1]; o[2] = (_Float16)u[2]; o[3] = (_Float16)u[3];
    o[4] = (_Float16)w[0]; o[5] = (_Float16)w[1]; o[6] = (_Float16)w[2]; o[7] = (_Float16)w[3];
    return o;
}

// ---------------------------------------------------------------------------
// GEMM: C[M,N] = A[M,128] @ Wsel^T (+bias). MFMA f32_16x16x32_f16.
// PERM: col n pulls W row ((n&3)*128 + (n>>2)) -> XP gate-interleaved (4j+q).
// Validated R4-R7.
// ---------------------------------------------------------------------------
template <bool A_F16, bool PERM, bool OUT_F32>
__global__ __launch_bounds__(256) void gemm_k128(
    const void* __restrict__ Av, const float* __restrict__ W,
    const float* __restrict__ bias, void* __restrict__ Cout, int M, int N)
{
    const int lane = threadIdx.x & 63, wave = threadIdx.x >> 6;
    const int m0 = blockIdx.y * 64 + wave * 16;
    const int n0 = blockIdx.x * 64;
    const int r15 = lane & 15, kg = lane >> 4;

    f16x8 a[4];
    if (A_F16) {
        const f16x8* Ar = (const f16x8*)((const _Float16*)Av + (size_t)(m0 + r15) * 128);
#pragma unroll
        for (int kt = 0; kt < 4; kt++) a[kt] = Ar[kt * 4 + kg];
    } else {
        const float* Ar = (const float*)Av + (size_t)(m0 + r15) * 128;
#pragma unroll
        for (int kt = 0; kt < 4; kt++) a[kt] = cvt8(Ar + kt * 32 + kg * 8);
    }

    f16x8 bfrg[4][4];
#pragma unroll
    for (int nt = 0; nt < 4; nt++) {
        int n = n0 + nt * 16 + r15;
        int wrow = PERM ? ((n & 3) * 128 + (n >> 2)) : n;
        const float* Wr = W + (size_t)wrow * 128;
#pragma unroll
        for (int kt = 0; kt < 4; kt++) bfrg[nt][kt] = cvt8(Wr + kt * 32 + kg * 8);
    }

    float4v acc[4] = {};
#pragma unroll
    for (int kt = 0; kt < 4; kt++)
#pragma unroll
        for (int nt = 0; nt < 4; nt++)
            acc[nt] = __builtin_amdgcn_mfma_f32_16x16x32_f16(a[kt], bfrg[nt][kt], acc[nt], 0, 0, 0);

#pragma unroll
    for (int nt = 0; nt < 4; nt++) {
        int n = n0 + nt * 16 + r15;
        float bv = bias ? bias[n] : 0.f;
#pragma unroll
        for (int r = 0; r < 4; r++) {
            int m = m0 + kg * 4 + r;
            float v = acc[nt][r] + bv;
            if (OUT_F32) ((float*)Cout)[(size_t)m * N + n] = v;
            else         ((_Float16*)Cout)[(size_t)m * N + n] = (_Float16)v;
        }
    }
}

// ---------------------------------------------------------------------------
// R12: producer de-stalled.
// R11 post-mortem: consumer restructure = exact zero delta -> consumer is NOT
// the limiter; producer runs ~857ns/step fused vs 663 standalone. Theory: the
// divergent publish block (shfl + guarded store) + per-step release branch
// with inline-asm vmcnt defeat the compiler's precise per-wave waitcnt
// tracking -> conservative vmcnt before each xp consume waits on the PREVIOUS
// step's agent-store ACK (~500-900cy at the coherence point) EVERY step. Fix:
//   - granule loop: branch-free straight-line 8-step inner body (unrolled);
//     waitcnt tracking stays precise, stores stay fire-and-forget.
//   - per-lane u16 agent store (all 64 lanes, own j): no ds_bpermute, no
//     divergent guard; same wave segment pattern (4 x 32B).
//   - xp prefetch UNCONDITIONAL (last step over-reads 8B into the adjacent
//     Y ws region -- in bounds, never consumed): no conditional VMEM op.
//   - release at granule end: vmcnt(2)/(1) leaves only newest {xpload,
//     ystore} -> y(0..8g+6) ACKed -> prog=8g+7. SAME semantics as R10/R11:
//     consumer + host unchanged.
// Consumer branch verbatim R11 (pipelined ih, triple-buffered y staging).
// ---------------------------------------------------------------------------
template <bool P_HAS_XP, bool P_INIT, bool C_INIT, bool C_WRITE_Y>
__global__ __launch_bounds__(512, 1) void lstm_fused2(
    const float* __restrict__ Up, const float* __restrict__ bip, const float* __restrict__ bhp,
    const _Float16* __restrict__ XPp,
    const float* __restrict__ php, const float* __restrict__ pcp,
    float* __restrict__ fhp, float* __restrict__ fcp,
    const float* __restrict__ Wc, const float* __restrict__ Uc,
    const float* __restrict__ bic, const float* __restrict__ bhc,
    const float* __restrict__ phc, const float* __restrict__ pcc,
    float* __restrict__ fhc, float* __restrict__ fcc,
    _Float16* __restrict__ PB,          // publish buffer [B,T,128] f16
    _Float16* __restrict__ Yc,          // consumer plain y out (or null)
    unsigned int* __restrict__ prog, int T)
{
    const int tid  = threadIdx.x;
    const int lane = tid & 63, w = tid >> 6;
    const int col  = lane & 15, quad = lane >> 4;
    const int b    = col & 3, s = col >> 2;
    const bool isC = blockIdx.x >= 16;
    const int p    = blockIdx.x & 15;
    const int bglob = p * 4 + b;
    const int j    = w * 16 + s * 4 + quad;

    __shared__ alignas(16) _Float16 Hl[2 * 4 * HSTR];
    __shared__ alignas(16) _Float16 Yl[3][4 * HSTR];   // y(t) triple buffer (consumer)
    const int SLAB = 4 * HSTR * 2;                     // slab stride, bytes

    unsigned int* pr = prog + p * 16;   // 64B stride: no shared-line hammering

    if (!isC) {
        // ================= producer (granule-structured, R12) =============
        f16x8 af[4][4];
#pragma unroll
        for (int mt = 0; mt < 4; mt++) {
            int urow = (col & 3) * 128 + (w * 16 + mt * 4 + (col >> 2));
            const float* ur = Up + (size_t)urow * 128;
#pragma unroll
            for (int kc = 0; kc < 4; kc++) af[mt][kc] = cvt8(ur + kc * 32 + quad * 8);
        }
#pragma unroll
        for (int mt = 0; mt < 4; mt++)
#pragma unroll
            for (int kc = 0; kc < 4; kc++) pin(af[mt][kc]);

        float bq[4];
#pragma unroll
        for (int q = 0; q < 4; q++) bq[q] = bip[q * 128 + j] + bhp[q * 128 + j];

        float c = 0.f, hv = 0.f;
        if (P_INIT) {
            c  = pcp[(size_t)bglob * 128 + j];
            hv = php[(size_t)bglob * 128 + j];
        }
        Hl[b * HSTR + j] = (_Float16)hv;
        __syncthreads();

        const _Float16* xb = P_HAS_XP ? XPp + ((size_t)bglob * T) * 512 + 4 * j : nullptr;
        unsigned short* pbp = (unsigned short*)(PB + (size_t)bglob * T * 128 + j);
        f16x4 xp = {};
        if (P_HAS_XP) xp = *(const f16x4*)xb;

        int cur = 0;
        const int NG = T >> 3;                         // T % 8 == 0 (T=2048)
        for (int g = 0; g < NG; g++) {
#pragma unroll
            for (int k = 0; k < 8; k++) {
                const int t = g * 8 + k;
                // UNCONDITIONAL prefetch: t=T-1 over-reads 8B into the Y ws
                // region (in bounds, never consumed). Keeps the body free of
                // conditional VMEM ops -> precise waitcnt tracking.
                f16x4 xpn = {};
                if (P_HAS_XP) xpn = *(const f16x4*)(xb + (size_t)(t + 1) * 512);

                const _Float16* Hc = Hl + cur * (4 * HSTR);
                f16x8 bf[4];
#pragma unroll
                for (int kc = 0; kc < 4; kc++)
                    bf[kc] = *(const f16x8*)(Hc + b * HSTR + kc * 32 + quad * 8);

                float4v acc[4] = {};
#pragma unroll
                for (int kc = 0; kc < 4; kc++)
#pragma unroll
                    for (int mt = 0; mt < 4; mt++)
                        acc[mt] = __builtin_amdgcn_mfma_f32_16x16x32_f16(af[mt][kc], bf[kc], acc[mt], 0, 0, 0);

                float4v t0 = (s & 1) ? acc[1] : acc[0];
                float4v t1 = (s & 1) ? acc[3] : acc[2];
                float4v gg = (s & 2) ? t1 : t0;

                float g0 = gg[0] + bq[0], g1 = gg[1] + bq[1], g2 = gg[2] + bq[2], g3 = gg[3] + bq[3];
                if (P_HAS_XP) { g0 += (float)xp[0]; g1 += (float)xp[1]; g2 += (float)xp[2]; g3 += (float)xp[3]; }
                float iv = sigf_fast(g0), fv = sigf_fast(g1);
                float gv = tanhf_fast(g2), ov = sigf_fast(g3);
                c  = fv * c + iv * gv;
                hv = ov * tanhf_fast(c);

                _Float16 hf = (_Float16)hv;
                Hl[(cur ^ 1) * (4 * HSTR) + b * HSTR + j] = hf;

                // per-lane u16 agent publish: no shfl, no divergence.
                __hip_atomic_store(pbp + (size_t)t * 128,
                                   __builtin_bit_cast(unsigned short, hf),
                                   __ATOMIC_RELAXED, __HIP_MEMORY_SCOPE_AGENT);

                lds_barrier();
                xp = xpn;
                cur ^= 1;
            }
            // granule release: leave only the newest {xpload, ystore}
            // outstanding -> y(0..8g+6) ACKed at the coherence point.
            if constexpr (P_HAS_XP) asm volatile("s_waitcnt vmcnt(2)" ::: "memory");
            else                    asm volatile("s_waitcnt vmcnt(1)" ::: "memory");
            if (tid == 0)
                __hip_atomic_store(pr, (unsigned int)(g * 8 + 7),
                                   __ATOMIC_RELAXED, __HIP_MEMORY_SCOPE_AGENT);
        }

        asm volatile("s_waitcnt vmcnt(0)" ::: "memory");
        __syncthreads();
        if (tid == 0)
            __hip_atomic_store(pr, (unsigned int)T, __ATOMIC_RELAXED, __HIP_MEMORY_SCOPE_AGENT);

        fhp[(size_t)bglob * 128 + j] = hv;
        fcp[(size_t)bglob * 128 + j] = c;
    } else {
        // ======== consumer: verbatim R11 (pipelined ih, triple-buffer) =====
        f16x8 afI[4][4], afH[4][4];
#pragma unroll
        for (int mt = 0; mt < 4; mt++) {
            int urow = (col & 3) * 128 + (w * 16 + mt * 4 + (col >> 2));
            const float* wr = Wc + (size_t)urow * 128;
            const float* ur = Uc + (size_t)urow * 128;
#pragma unroll
            for (int kc = 0; kc < 4; kc++) {
                afI[mt][kc] = cvt8(wr + kc * 32 + quad * 8);
                afH[mt][kc] = cvt8(ur + kc * 32 + quad * 8);
            }
        }
#pragma unroll
        for (int mt = 0; mt < 4; mt++)
#pragma unroll
            for (int kc = 0; kc < 4; kc++) { pin(afI[mt][kc]); pin(afH[mt][kc]); }

        float bq[4];
#pragma unroll
        for (int q = 0; q < 4; q++) bq[q] = bic[q * 128 + j] + bhc[q * 128 + j];

        float c = 0.f, hv = 0.f;
        if (C_INIT) {
            c  = pcc[(size_t)bglob * 128 + j];
            hv = phc[(size_t)bglob * 128 + j];
        }
        Hl[b * HSTR + j] = (_Float16)hv;

        // loader mapping: tid<128 -> one unique u64 of the 1KB y row
        const bool isLoader = (tid < 128);
        const int lb = (tid >> 5) & 3, lc = tid & 31;
        const _Float16* lyb = PB + ((size_t)(p * 4 + lb) * T) * 128 + lc * 4;
        char* lws = (char*)&Yl[0][0];
        const int lo = lb * (HSTR * 2) + lc * 8;   // byte offset within a slab

        // pre-loop poller: y(0..2) pre-stage needs prog>=3; step-0 load of
        // y(3) needs prog>=4.
        unsigned int psn = 0;
        if (tid == 511) {
            unsigned int need0 = (T < 4) ? (unsigned int)T : 4u;
            psn = __hip_atomic_load(pr, __ATOMIC_RELAXED, __HIP_MEMORY_SCOPE_AGENT);
            while (psn < need0) {
                __builtin_amdgcn_s_sleep(8);
                psn = __hip_atomic_load(pr, __ATOMIC_RELAXED, __HIP_MEMORY_SCOPE_AGENT);
            }
        }
        __syncthreads();

        // pre-stage y(0), y(1), y(2) into slabs 0,1,2
        if (isLoader) {
            if (T > 0) {
                u64 v0 = __hip_atomic_load((const u64*)lyb, __ATOMIC_RELAXED, __HIP_MEMORY_SCOPE_AGENT);
                *(u64*)(lws + 0 * SLAB + lo) = v0;
            }
            if (T > 1) {
                u64 v1 = __hip_atomic_load((const u64*)(lyb + 128), __ATOMIC_RELAXED, __HIP_MEMORY_SCOPE_AGENT);
                *(u64*)(lws + 1 * SLAB + lo) = v1;
            }
            if (T > 2) {
                u64 v2 = __hip_atomic_load((const u64*)(lyb + 256), __ATOMIC_RELAXED, __HIP_MEMORY_SCOPE_AGENT);
                *(u64*)(lws + 2 * SLAB + lo) = v2;
            }
        }
        lds_barrier();

        // prime accI for step 0 from y(0)
        float4v accI[4] = {};
        if (T > 0) {
            const _Float16* Yb = (const _Float16*)(lws + 0 * SLAB);
            f16x8 yf[4];
#pragma unroll
            for (int kc = 0; kc < 4; kc++)
                yf[kc] = *(const f16x8*)(Yb + b * HSTR + kc * 32 + quad * 8);
#pragma unroll
            for (int kc = 0; kc < 4; kc++)
#pragma unroll
                for (int mt = 0; mt < 4; mt++)
                    accI[mt] = __builtin_amdgcn_mfma_f32_16x16x32_f16(afI[mt][kc], yf[kc], accI[mt], 0, 0, 0);
        }

        u64 yv = 0;
        int cur = 0;
        int sW = 2, sR = 1;   // at step t: write slab (t+2)%3, read slab (t+1)%3
        for (int t = 0; t < T; t++) {
            // stage y(t+2) (loaded during step t-1); t==0 was pre-staged.
            if (isLoader && t >= 1 && (t + 2 < T))
                *(u64*)(lws + sW * SLAB + lo) = yv;
            // issue load y(t+3): consumed at top of step t+1
            if (isLoader && (t + 3 < T))
                yv = __hip_atomic_load((const u64*)(lyb + (size_t)(t + 3) * 128),
                                       __ATOMIC_RELAXED, __HIP_MEMORY_SCOPE_AGENT);

            // ---- recurrence critical path: hh chain only ----
            const _Float16* Hc = Hl + cur * (4 * HSTR);
            f16x8 bf[4];
#pragma unroll
            for (int kc = 0; kc < 4; kc++)
                bf[kc] = *(const f16x8*)(Hc + b * HSTR + kc * 32 + quad * 8);

            float4v accH[4] = {};
#pragma unroll
            for (int kc = 0; kc < 4; kc++)
#pragma unroll
                for (int mt = 0; mt < 4; mt++)
                    accH[mt] = __builtin_amdgcn_mfma_f32_16x16x32_f16(afH[mt][kc], bf[kc], accH[mt], 0, 0, 0);

            float4v i0 = (s & 1) ? accI[1] : accI[0];
            float4v i1 = (s & 1) ? accI[3] : accI[2];
            float4v gI = (s & 2) ? i1 : i0;
            float4v h0 = (s & 1) ? accH[1] : accH[0];
            float4v h1 = (s & 1) ? accH[3] : accH[2];
            float4v gH = (s & 2) ? h1 : h0;

            float g0 = gI[0] + gH[0] + bq[0], g1 = gI[1] + gH[1] + bq[1];
            float g2 = gI[2] + gH[2] + bq[2], g3 = gI[3] + gH[3] + bq[3];
            float iv = sigf_fast(g0), fv = sigf_fast(g1);
            float gv = tanhf_fast(g2), ov = sigf_fast(g3);
            c  = fv * c + iv * gv;
            hv = ov * tanhf_fast(c);

            Hl[(cur ^ 1) * (4 * HSTR) + b * HSTR + j] = (_Float16)hv;
            if (C_WRITE_Y)
                Yc[((size_t)bglob * T + t) * 128 + j] = (_Float16)hv;

            // ---- off-path: accI(t+1) = Wih @ y(t+1), fills idle MFMA slots
            float4v accN[4] = {};
            if (t + 1 < T) {
                const _Float16* Yb = (const _Float16*)(lws + sR * SLAB);
                f16x8 yf[4];
#pragma unroll
                for (int kc = 0; kc < 4; kc++)
                    yf[kc] = *(const f16x8*)(Yb + b * HSTR + kc * 32 + quad * 8);
#pragma unroll
                for (int kc = 0; kc < 4; kc++)
#pragma unroll
                    for (int mt = 0; mt < 4; mt++)
                        accN[mt] = __builtin_amdgcn_mfma_f32_16x16x32_f16(afI[mt][kc], yf[kc], accN[mt], 0, 0, 0);
            }

            // poller: during step t, guarantee step t+1's load (y(t+4)).
            if (tid == 511 && (t + 4 < T)) {
                unsigned int need = (unsigned int)(t + 5);
                if (psn < need) {
                    psn = __hip_atomic_load(pr, __ATOMIC_RELAXED, __HIP_MEMORY_SCOPE_AGENT);
                    while (psn < need) {
                        __builtin_amdgcn_s_sleep(2);
                        psn = __hip_atomic_load(pr, __ATOMIC_RELAXED, __HIP_MEMORY_SCOPE_AGENT);
                    }
                }
            }
            lds_barrier();

#pragma unroll
            for (int mt = 0; mt < 4; mt++) accI[mt] = accN[mt];
            cur ^= 1;
            sW = (sW == 2) ? 0 : sW + 1;
            sR = (sR == 2) ? 0 : sR + 1;
        }

        fhc[(size_t)bglob * 128 + j] = hv;
        fcc[(size_t)bglob * 128 + j] = c;
    }
}

// ---------------------------------------------------------------------------
// Host side: memset + 4 stream-ordered launches.
//   ws: XP f16 [131072,512] perm (128MB) | Y f16 [131072,128] (32MB) | finals
//   prog counters: first 2KB of d_out (64B stride x 16 x 2 phases), dead
//   scratch until the final GEMM overwrites it.
// ---------------------------------------------------------------------------
extern "C" void kernel_launch(void* const* d_in, const int* in_sizes, int n_in,
                              void* d_out, int out_size, void* d_ws, size_t ws_size,
                              hipStream_t stream)
{
    const float* x    = (const float*)d_in[0];
    const float* eW0  = (const float*)d_in[1];
    const float* eU0  = (const float*)d_in[2];
    const float* eb0i = (const float*)d_in[3];
    const float* eb0h = (const float*)d_in[4];
    const float* eW1  = (const float*)d_in[5];
    const float* eU1  = (const float*)d_in[6];
    const float* eb1i = (const float*)d_in[7];
    const float* eb1h = (const float*)d_in[8];
    const float* dU0  = (const float*)d_in[10];
    const float* db0i = (const float*)d_in[11];
    const float* db0h = (const float*)d_in[12];
    const float* dW1  = (const float*)d_in[13];
    const float* dU1  = (const float*)d_in[14];
    const float* db1i = (const float*)d_in[15];
    const float* db1h = (const float*)d_in[16];
    const float* oW   = (const float*)d_in[17];
    const float* ob   = (const float*)d_in[18];

    char* ws = (char*)d_ws;
    _Float16* XP  = (_Float16*)ws;                              // 134217728 B
    _Float16* Y   = (_Float16*)(ws + 134217728);                //  33554432 B
    float*    fh0 = (float*)(ws + 167772160);
    float*    fc0 = fh0 + Bsz * Hd;
    float*    fh1 = fc0 + Bsz * Hd;
    float*    fc1 = fh1 + Bsz * Hd;

    unsigned int* progA = (unsigned int*)d_out;     // 16 x 64B
    unsigned int* progB = progA + 16 * 16;          // 16 x 64B

    dim3 blk(256);
    dim3 gXP(G4 / 64, Mrows / 64);    // (8, 2048)
    dim3 gOut(Hd / 64, Mrows / 64);   // (2, 2048)

    // zero progress counters (graph-safe, re-zeroed every replay)
    hipMemsetAsync(d_out, 0, 2048, stream);

    // 1) XP = x @ enc_Wih0^T (permuted, f16)
    gemm_k128<false, true, false><<<gXP, blk, 0, stream>>>((const void*)x, eW0, (const float*)nullptr, (void*)XP, Mrows, G4);

    // 2) encoder phase: encL0 (producer) || encL1 (consumer, dual matvec)
    lstm_fused2<true, false, false, false><<<dim3(32), dim3(512), 0, stream>>>(
        eU0, eb0i, eb0h, XP, (const float*)nullptr, (const float*)nullptr, fh0, fc0,
        eW1, eU1, eb1i, eb1h, (const float*)nullptr, (const float*)nullptr, fh1, fc1,
        Y, (_Float16*)nullptr, progA, Tlen);

    // 3) decoder phase: decL0 (producer, zero input, init enc finals) ||
    //    decL1 (consumer, init enc finals, writes final y to Y)
    lstm_fused2<false, true, true, true><<<dim3(32), dim3(512), 0, stream>>>(
        dU0, db0i, db0h, (const _Float16*)nullptr, fh0, fc0, fh0, fc0,
        dW1, dU1, db1i, db1h, fh1, fc1, fh1, fc1,
        XP /*publish scratch*/, Y, progB, Tlen);

    // 4) out = d1 @ out_W^T + out_b (f32 -> d_out, overwrites prog scratch)
    gemm_k128<true, false, true><<<gOut, blk, 0, stream>>>((const void*)Y, oW, ob, d_out, Mrows, Hd);
}

// Round 5
// 2707.935 us; speedup vs baseline: 1.4330x; 1.4095x over previous
//
#include <hip/hip_runtime.h>
#include <cstdint>
#include <cstddef>

typedef float    float4v __attribute__((ext_vector_type(4)));
typedef _Float16 f16x4   __attribute__((ext_vector_type(4)));
typedef _Float16 f16x8   __attribute__((ext_vector_type(8)));
typedef unsigned long long u64;

#define DI __device__ __forceinline__

static const int Bsz = 64, Tlen = 2048, Hd = 128, G4 = 512;  // 4H=512
static const int Mrows = Bsz * Tlen;                          // 131072
static const int HSTR = 144;   // H row stride (f16): 0 bank conflicts, validated R7
static const int RING = 256;   // y/XP2 ring length (steps); lag bound ~4 granules << 256
static const int YSTR = 136;   // helper LDS y row stride (f16): 2-way conflict only (free)

DI float sigf_fast(float x) {
    float e = __builtin_amdgcn_exp2f(-1.442695041f * x);
    return __builtin_amdgcn_rcpf(1.f + e);
}
DI float tanhf_fast(float x) {
    float e = __builtin_amdgcn_exp2f(-2.885390082f * x);
    return 2.f * __builtin_amdgcn_rcpf(1.f + e) - 1.f;
}

// LDS-only barrier: no vmcnt drain (validated R5, -24%).
DI void lds_barrier() {
    asm volatile("s_waitcnt lgkmcnt(0)\n\ts_barrier" ::: "memory");
}

// Pin a 128-bit fragment in VGPRs (forbids weight rematerialization; R8).
DI void pin(f16x8& v) {
    float4v t = __builtin_bit_cast(float4v, v);
    asm volatile("" : "+v"(t));
    v = __builtin_bit_cast(f16x8, t);
}

// load 8 consecutive f32, convert to f16x8
DI f16x8 cvt8(const float* p) {
    float4v u = *(const float4v*)p;
    float4v w = *(const float4v*)(p + 4);
    f16x8 o;
    o[0] = (_Float16)u[0]; o[1] = (_Float16)u[1]; o[2] = (_Float16)u[2]; o[3] = (_Float16)u[3];
    o[4] = (_Float16)w[0]; o[5] = (_Float16)w[1]; o[6] = (_Float16)w[2]; o[7] = (_Float16)w[3];
    return o;
}

DI u64 ald64(const void* pp) {
    return __hip_atomic_load((const u64*)pp, __ATOMIC_RELAXED, __HIP_MEMORY_SCOPE_AGENT);
}
DI void ast16(void* pp, unsigned short v) {
    __hip_atomic_store((unsigned short*)pp, v, __ATOMIC_RELAXED, __HIP_MEMORY_SCOPE_AGENT);
}
DI unsigned int aldu32(const unsigned int* pp) {
    return __hip_atomic_load(pp, __ATOMIC_RELAXED, __HIP_MEMORY_SCOPE_AGENT);
}
DI void astu32(unsigned int* pp, unsigned int v) {
    __hip_atomic_store(pp, v, __ATOMIC_RELAXED, __HIP_MEMORY_SCOPE_AGENT);
}

// ---------------------------------------------------------------------------
// GEMM: C[M,N] = A[M,128] @ Wsel^T (+bias). MFMA f32_16x16x32_f16.
// PERM: col n pulls W row ((n&3)*128 + (n>>2)) -> XP gate-interleaved (4j+q).
// Validated R4-R7.
// ---------------------------------------------------------------------------
template <bool A_F16, bool PERM, bool OUT_F32>
__global__ __launch_bounds__(256) void gemm_k128(
    const void* __restrict__ Av, const float* __restrict__ W,
    const float* __restrict__ bias, void* __restrict__ Cout, int M, int N)
{
    const int lane = threadIdx.x & 63, wave = threadIdx.x >> 6;
    const int m0 = blockIdx.y * 64 + wave * 16;
    const int n0 = blockIdx.x * 64;
    const int r15 = lane & 15, kg = lane >> 4;

    f16x8 a[4];
    if (A_F16) {
        const f16x8* Ar = (const f16x8*)((const _Float16*)Av + (size_t)(m0 + r15) * 128);
#pragma unroll
        for (int kt = 0; kt < 4; kt++) a[kt] = Ar[kt * 4 + kg];
    } else {
        const float* Ar = (const float*)Av + (size_t)(m0 + r15) * 128;
#pragma unroll
        for (int kt = 0; kt < 4; kt++) a[kt] = cvt8(Ar + kt * 32 + kg * 8);
    }

    f16x8 bfrg[4][4];
#pragma unroll
    for (int nt = 0; nt < 4; nt++) {
        int n = n0 + nt * 16 + r15;
        int wrow = PERM ? ((n & 3) * 128 + (n >> 2)) : n;
        const float* Wr = W + (size_t)wrow * 128;
#pragma unroll
        for (int kt = 0; kt < 4; kt++) bfrg[nt][kt] = cvt8(Wr + kt * 32 + kg * 8);
    }

    float4v acc[4] = {};
#pragma unroll
    for (int kt = 0; kt < 4; kt++)
#pragma unroll
        for (int nt = 0; nt < 4; nt++)
            acc[nt] = __builtin_amdgcn_mfma_f32_16x16x32_f16(a[kt], bfrg[nt][kt], acc[nt], 0, 0, 0);

#pragma unroll
    for (int nt = 0; nt < 4; nt++) {
        int n = n0 + nt * 16 + r15;
        float bv = bias ? bias[n] : 0.f;
#pragma unroll
        for (int r = 0; r < 4; r++) {
            int m = m0 + kg * 4 + r;
            float v = acc[nt][r] + bv;
            if (OUT_F32) ((float*)Cout)[(size_t)m * N + n] = v;
            else         ((_Float16*)Cout)[(size_t)m * N + n] = (_Float16)v;
        }
    }
}

// ---------------------------------------------------------------------------
// R13: 3-stage pipeline producer -> helper -> consumer. 48 WGs x 512 thr.
// R12 post-mortem: consumer (dual matvec) is the pace-setter (~825ns/step);
// in-place thinning failed twice. Move the NON-recurrent ih-matvec into 16
// helper WGs: XP2(t) = Wih_c @ y0(t), computed in 8-step granule GEMM bursts
// lagging the producer. Consumer becomes a CLONE of the validated producer
// loop (prefetch 8B xp2 quad + 16 hh-MFMAs + VALU + 1 barrier).
//   role 0 (WG 0-15):  producer, R12 body, publishes y into 256-step ring.
//   role 2 (WG 32-47): helper, per granule: poll prog>=8g+8, stage y granule
//                      to LDS (512 unique 16B sc1 loads), 256-MFMA GEMM with
//                      pinned PERM Wih frags, scatter u16 sc1 stores to XP2
//                      ring, vmcnt(0), release prog2=8g+8.
//   role 1 (WG 16-31): consumer, granule-paced: poller tid511 ensures
//                      prog2 >= 8(g+1)+9 during granule g; branch-free 8-step
//                      body identical to producer's minus publish.
// Rings (RING=256): overwrite-before-read impossible by construction
// (helper lag <= ~3 granules, consumer <= ~4; ring = 32 granules).
// ---------------------------------------------------------------------------
template <bool P_HAS_XP, bool P_INIT, bool C_INIT, bool C_WRITE_Y>
__global__ __launch_bounds__(512, 1) void lstm_fused3(
    const float* __restrict__ Up, const float* __restrict__ bip, const float* __restrict__ bhp,
    const _Float16* __restrict__ XPp,
    const float* __restrict__ php, const float* __restrict__ pcp,
    float* __restrict__ fhp, float* __restrict__ fcp,
    const float* __restrict__ Wc, const float* __restrict__ Uc,
    const float* __restrict__ bic, const float* __restrict__ bhc,
    const float* __restrict__ phc, const float* __restrict__ pcc,
    float* __restrict__ fhc, float* __restrict__ fcc,
    _Float16* __restrict__ PB,          // y ring   [64][RING][128] f16
    _Float16* __restrict__ X2,          // XP2 ring [64][RING][512] f16 (PERM 4j+q)
    _Float16* __restrict__ Yc,          // consumer plain y out (or null)
    unsigned int* __restrict__ prog, unsigned int* __restrict__ prog2, int T)
{
    const int tid  = threadIdx.x;
    const int lane = tid & 63, w = tid >> 6;
    const int col  = lane & 15, quad = lane >> 4;
    const int b    = col & 3, s = col >> 2;
    const int role = blockIdx.x >> 4;            // 0 prod, 1 cons, 2 helper
    const int p    = blockIdx.x & 15;
    const int bglob = p * 4 + b;
    const int j    = w * 16 + s * 4 + quad;
    const int NG   = T >> 3;                     // T % 8 == 0

    __shared__ alignas(16) _Float16 Hl[2 * 4 * HSTR];
    __shared__ alignas(16) _Float16 Ylh[32 * YSTR];   // helper y granule stage

    unsigned int* pr  = prog  + p * 16;   // 64B stride
    unsigned int* pr2 = prog2 + p * 16;

    if (role == 0) {
        // ================= producer (R12 body + ring slot) ================
        f16x8 af[4][4];
#pragma unroll
        for (int mt = 0; mt < 4; mt++) {
            int urow = (col & 3) * 128 + (w * 16 + mt * 4 + (col >> 2));
            const float* ur = Up + (size_t)urow * 128;
#pragma unroll
            for (int kc = 0; kc < 4; kc++) af[mt][kc] = cvt8(ur + kc * 32 + quad * 8);
        }
#pragma unroll
        for (int mt = 0; mt < 4; mt++)
#pragma unroll
            for (int kc = 0; kc < 4; kc++) pin(af[mt][kc]);

        float bq[4];
#pragma unroll
        for (int q = 0; q < 4; q++) bq[q] = bip[q * 128 + j] + bhp[q * 128 + j];

        float c = 0.f, hv = 0.f;
        if (P_INIT) {
            c  = pcp[(size_t)bglob * 128 + j];
            hv = php[(size_t)bglob * 128 + j];
        }
        Hl[b * HSTR + j] = (_Float16)hv;
        __syncthreads();

        const _Float16* xb = P_HAS_XP ? XPp + ((size_t)bglob * T) * 512 + 4 * j : nullptr;
        unsigned short* pbp = (unsigned short*)PB + (size_t)bglob * RING * 128 + j;
        f16x4 xp = {};
        if (P_HAS_XP) xp = *(const f16x4*)xb;

        int cur = 0;
        for (int g = 0; g < NG; g++) {
#pragma unroll
            for (int k = 0; k < 8; k++) {
                const int t = g * 8 + k;
                // unconditional prefetch (t=T-1 over-reads 8B, in-bounds, unused)
                f16x4 xpn = {};
                if (P_HAS_XP) xpn = *(const f16x4*)(xb + (size_t)(t + 1) * 512);

                const _Float16* Hc = Hl + cur * (4 * HSTR);
                f16x8 bf[4];
#pragma unroll
                for (int kc = 0; kc < 4; kc++)
                    bf[kc] = *(const f16x8*)(Hc + b * HSTR + kc * 32 + quad * 8);

                float4v acc[4] = {};
#pragma unroll
                for (int kc = 0; kc < 4; kc++)
#pragma unroll
                    for (int mt = 0; mt < 4; mt++)
                        acc[mt] = __builtin_amdgcn_mfma_f32_16x16x32_f16(af[mt][kc], bf[kc], acc[mt], 0, 0, 0);

                float4v t0 = (s & 1) ? acc[1] : acc[0];
                float4v t1 = (s & 1) ? acc[3] : acc[2];
                float4v gg = (s & 2) ? t1 : t0;

                float g0 = gg[0] + bq[0], g1 = gg[1] + bq[1], g2 = gg[2] + bq[2], g3 = gg[3] + bq[3];
                if (P_HAS_XP) { g0 += (float)xp[0]; g1 += (float)xp[1]; g2 += (float)xp[2]; g3 += (float)xp[3]; }
                float iv = sigf_fast(g0), fv = sigf_fast(g1);
                float gv = tanhf_fast(g2), ov = sigf_fast(g3);
                c  = fv * c + iv * gv;
                hv = ov * tanhf_fast(c);

                _Float16 hf = (_Float16)hv;
                Hl[(cur ^ 1) * (4 * HSTR) + b * HSTR + j] = hf;

                // per-lane u16 agent publish into the ring
                ast16(pbp + (size_t)(t & (RING - 1)) * 128,
                      __builtin_bit_cast(unsigned short, hf));

                lds_barrier();
                xp = xpn;
                cur ^= 1;
            }
            // granule release: only newest {xpload, ystore} may remain
            // outstanding -> y(0..8g+6) ACKed. prog = count of ready steps.
            if constexpr (P_HAS_XP) asm volatile("s_waitcnt vmcnt(2)" ::: "memory");
            else                    asm volatile("s_waitcnt vmcnt(1)" ::: "memory");
            if (tid == 0) astu32(pr, (unsigned int)(g * 8 + 7));
        }

        asm volatile("s_waitcnt vmcnt(0)" ::: "memory");
        __syncthreads();
        if (tid == 0) astu32(pr, (unsigned int)T);

        fhp[(size_t)bglob * 128 + j] = hv;
        fcp[(size_t)bglob * 128 + j] = c;
    } else if (role == 1) {
        // ================= consumer (thin: producer clone on xp2) =========
        f16x8 afH[4][4];
#pragma unroll
        for (int mt = 0; mt < 4; mt++) {
            int urow = (col & 3) * 128 + (w * 16 + mt * 4 + (col >> 2));
            const float* ur = Uc + (size_t)urow * 128;
#pragma unroll
            for (int kc = 0; kc < 4; kc++) afH[mt][kc] = cvt8(ur + kc * 32 + quad * 8);
        }
#pragma unroll
        for (int mt = 0; mt < 4; mt++)
#pragma unroll
            for (int kc = 0; kc < 4; kc++) pin(afH[mt][kc]);

        float bq[4];
#pragma unroll
        for (int q = 0; q < 4; q++) bq[q] = bic[q * 128 + j] + bhc[q * 128 + j];

        float c = 0.f, hv = 0.f;
        if (C_INIT) {
            c  = pcc[(size_t)bglob * 128 + j];
            hv = phc[(size_t)bglob * 128 + j];
        }
        Hl[b * HSTR + j] = (_Float16)hv;

        // pre-poll: granule-0 prefetches reach xp2 index 8 -> prog2 >= 9
        if (tid == 511) {
            unsigned int need = 9u; if (need > (unsigned int)T) need = (unsigned int)T;
            unsigned int psn = aldu32(pr2);
            while (psn < need) { __builtin_amdgcn_s_sleep(8); psn = aldu32(pr2); }
        }
        __syncthreads();

        const _Float16* x2b = X2 + (size_t)bglob * RING * 512 + 4 * j;
        f16x4 xp = __builtin_bit_cast(f16x4, ald64(x2b));   // xp2(0), slot 0

        int cur = 0;
        for (int g = 0; g < NG; g++) {
#pragma unroll
            for (int k = 0; k < 8; k++) {
                const int t = g * 8 + k;
                const int slot = (t + 1) & (RING - 1);
                f16x4 xpn = __builtin_bit_cast(f16x4, ald64(x2b + (size_t)slot * 512));

                const _Float16* Hc = Hl + cur * (4 * HSTR);
                f16x8 bf[4];
#pragma unroll
                for (int kc = 0; kc < 4; kc++)
                    bf[kc] = *(const f16x8*)(Hc + b * HSTR + kc * 32 + quad * 8);

                float4v acc[4] = {};
#pragma unroll
                for (int kc = 0; kc < 4; kc++)
#pragma unroll
                    for (int mt = 0; mt < 4; mt++)
                        acc[mt] = __builtin_amdgcn_mfma_f32_16x16x32_f16(afH[mt][kc], bf[kc], acc[mt], 0, 0, 0);

                float4v t0 = (s & 1) ? acc[1] : acc[0];
                float4v t1 = (s & 1) ? acc[3] : acc[2];
                float4v gg = (s & 2) ? t1 : t0;

                float g0 = gg[0] + bq[0] + (float)xp[0], g1 = gg[1] + bq[1] + (float)xp[1];
                float g2 = gg[2] + bq[2] + (float)xp[2], g3 = gg[3] + bq[3] + (float)xp[3];
                float iv = sigf_fast(g0), fv = sigf_fast(g1);
                float gv = tanhf_fast(g2), ov = sigf_fast(g3);
                c  = fv * c + iv * gv;
                hv = ov * tanhf_fast(c);

                _Float16 hf = (_Float16)hv;
                Hl[(cur ^ 1) * (4 * HSTR) + b * HSTR + j] = hf;
                if (C_WRITE_Y)
                    Yc[((size_t)bglob * T + t) * 128 + j] = hf;

                lds_barrier();
                xp = xpn;
                cur ^= 1;
            }
            // poller: during granule g, guarantee granule g+1's prefetches
            // (xp2 indices up to 8(g+1)+8) -> prog2 >= 8(g+1)+9 (capped T).
            if (tid == 511 && g + 1 < NG) {
                unsigned int need = (unsigned int)(8 * (g + 1) + 9);
                if (need > (unsigned int)T) need = (unsigned int)T;
                unsigned int psn = aldu32(pr2);
                while (psn < need) { __builtin_amdgcn_s_sleep(2); psn = aldu32(pr2); }
            }
            lds_barrier();   // handoff before next granule's prefetches
        }

        fhc[(size_t)bglob * 128 + j] = hv;
        fcc[(size_t)bglob * 128 + j] = c;
    } else {
        // ================= helper: XP2(t) = Wih_c @ y0(t), granule GEMM ====
        // B-frags: PERM Wih rows, pinned. wave w covers n-tiles 4w..4w+3.
        f16x8 bw[4][4];
#pragma unroll
        for (int nt = 0; nt < 4; nt++) {
            int n = (w * 4 + nt) * 16 + col;
            int wrow = (n & 3) * 128 + (n >> 2);
            const float* Wr = Wc + (size_t)wrow * 128;
#pragma unroll
            for (int kc = 0; kc < 4; kc++) bw[nt][kc] = cvt8(Wr + kc * 32 + quad * 8);
        }
#pragma unroll
        for (int nt = 0; nt < 4; nt++)
#pragma unroll
            for (int kc = 0; kc < 4; kc++) pin(bw[nt][kc]);

        // stage mapping: 512 threads x 16B = 32 rows x 256B (unique)
        const int lrow = tid >> 4, lchunk = tid & 15;      // row=(b,trow), chunk
        const int lb = lrow & 3, ltr = lrow >> 2;

        for (int g = 0; g < NG; g++) {
            if (tid == 0) {
                unsigned int need = (unsigned int)(g * 8 + 8);  // y(..8g+7) ACKed
                unsigned int psn = aldu32(pr);
                while (psn < need) { __builtin_amdgcn_s_sleep(4); psn = aldu32(pr); }
            }
            __syncthreads();
            {   // stage y granule into LDS (dedup: each thread one unique 16B)
                int slot = (g * 8 + ltr) & (RING - 1);
                const char* srcp = (const char*)(PB + ((size_t)(p * 4 + lb) * RING + slot) * 128 + lchunk * 8);
                u64 a0 = ald64(srcp);
                u64 a1 = ald64(srcp + 8);
                char* dst = (char*)&Ylh[lrow * YSTR + lchunk * 8];
                *(u64*)dst = a0;
                *(u64*)(dst + 8) = a1;
            }
            lds_barrier();

            float4v acc[2][4] = {};
#pragma unroll
            for (int kc = 0; kc < 4; kc++) {
                f16x8 a0 = *(const f16x8*)&Ylh[col * YSTR + kc * 32 + quad * 8];
                f16x8 a1 = *(const f16x8*)&Ylh[(16 + col) * YSTR + kc * 32 + quad * 8];
#pragma unroll
                for (int nt = 0; nt < 4; nt++) {
                    acc[0][nt] = __builtin_amdgcn_mfma_f32_16x16x32_f16(a0, bw[nt][kc], acc[0][nt], 0, 0, 0);
                    acc[1][nt] = __builtin_amdgcn_mfma_f32_16x16x32_f16(a1, bw[nt][kc], acc[1][nt], 0, 0, 0);
                }
            }

            // scatter stores: C row m=(b,trow) -> XP2[(p*4+b)][slot(g*8+trow)][n]
#pragma unroll
            for (int mt = 0; mt < 2; mt++)
#pragma unroll
                for (int nt = 0; nt < 4; nt++) {
                    int n = (w * 4 + nt) * 16 + col;
#pragma unroll
                    for (int r = 0; r < 4; r++) {
                        int m = mt * 16 + quad * 4 + r;
                        int bb = m & 3, trow = m >> 2;
                        int slot = (g * 8 + trow) & (RING - 1);
                        _Float16 hval = (_Float16)acc[mt][nt][r];
                        ast16(X2 + ((size_t)(p * 4 + bb) * RING + slot) * 512 + n,
                              __builtin_bit_cast(unsigned short, hval));
                    }
                }

            asm volatile("s_waitcnt vmcnt(0)" ::: "memory");   // all stores ACKed
            __syncthreads();                                    // all waves drained
            if (tid == 0) astu32(pr2, (unsigned int)(g * 8 + 8));
        }
    }
}

// ---------------------------------------------------------------------------
// Host: memset + 4 stream-ordered launches.
//   ws: [0,128MB) XP (phase A input; phase B y/XP2 rings)
//       [128MB,160MB) phase A y/XP2 rings; phase B Y output (final GEMM in)
//       [160MB,+128KB) finals
//   prog scratch: first 4KB of d_out (dead until final GEMM overwrites).
// ---------------------------------------------------------------------------
extern "C" void kernel_launch(void* const* d_in, const int* in_sizes, int n_in,
                              void* d_out, int out_size, void* d_ws, size_t ws_size,
                              hipStream_t stream)
{
    const float* x    = (const float*)d_in[0];
    const float* eW0  = (const float*)d_in[1];
    const float* eU0  = (const float*)d_in[2];
    const float* eb0i = (const float*)d_in[3];
    const float* eb0h = (const float*)d_in[4];
    const float* eW1  = (const float*)d_in[5];
    const float* eU1  = (const float*)d_in[6];
    const float* eb1i = (const float*)d_in[7];
    const float* eb1h = (const float*)d_in[8];
    const float* dU0  = (const float*)d_in[10];
    const float* db0i = (const float*)d_in[11];
    const float* db0h = (const float*)d_in[12];
    const float* dW1  = (const float*)d_in[13];
    const float* dU1  = (const float*)d_in[14];
    const float* db1i = (const float*)d_in[15];
    const float* db1h = (const float*)d_in[16];
    const float* oW   = (const float*)d_in[17];
    const float* ob   = (const float*)d_in[18];

    char* ws = (char*)d_ws;
    _Float16* XP   = (_Float16*)ws;                          // 128MB (phase A input)
    _Float16* Y    = (_Float16*)(ws + 134217728);            // 32MB (phase B output)
    _Float16* PB_A = (_Float16*)(ws + 134217728);            // y ring A: 4MB
    _Float16* X2_A = (_Float16*)(ws + 134217728 + 4194304);  // XP2 ring A: 16MB
    _Float16* PB_B = (_Float16*)ws;                          // y ring B: 4MB
    _Float16* X2_B = (_Float16*)(ws + 4194304);              // XP2 ring B: 16MB
    float*    fh0 = (float*)(ws + 167772160);
    float*    fc0 = fh0 + Bsz * Hd;
    float*    fh1 = fc0 + Bsz * Hd;
    float*    fc1 = fh1 + Bsz * Hd;

    unsigned int* progA  = (unsigned int*)d_out;       // 16 x 64B
    unsigned int* prog2A = progA + 16 * 16;
    unsigned int* progB  = progA + 32 * 16;
    unsigned int* prog2B = progA + 48 * 16;

    dim3 blk(256);
    dim3 gXP(G4 / 64, Mrows / 64);    // (8, 2048)
    dim3 gOut(Hd / 64, Mrows / 64);   // (2, 2048)

    // zero progress counters (graph-safe, re-zeroed every replay)
    hipMemsetAsync(d_out, 0, 4096, stream);

    // 1) XP = x @ enc_Wih0^T (permuted, f16)
    gemm_k128<false, true, false><<<gXP, blk, 0, stream>>>((const void*)x, eW0, (const float*)nullptr, (void*)XP, Mrows, G4);

    // 2) encoder: encL0 (prod) || Wih-helper || encL1 (cons)
    lstm_fused3<true, false, false, false><<<dim3(48), dim3(512), 0, stream>>>(
        eU0, eb0i, eb0h, XP, (const float*)nullptr, (const float*)nullptr, fh0, fc0,
        eW1, eU1, eb1i, eb1h, (const float*)nullptr, (const float*)nullptr, fh1, fc1,
        PB_A, X2_A, (_Float16*)nullptr, progA, prog2A, Tlen);

    // 3) decoder: decL0 (prod, zero input, init enc finals) || helper ||
    //    decL1 (cons, init enc finals, writes Y)
    lstm_fused3<false, true, true, true><<<dim3(48), dim3(512), 0, stream>>>(
        dU0, db0i, db0h, (const _Float16*)nullptr, fh0, fc0, fh0, fc0,
        dW1, dU1, db1i, db1h, fh1, fc1, fh1, fc1,
        PB_B, X2_B, Y, progB, prog2B, Tlen);

    // 4) out = d1 @ out_W^T + out_b (f32 -> d_out, overwrites prog scratch)
    gemm_k128<true, false, true><<<gOut, blk, 0, stream>>>((const void*)Y, oW, ob, d_out, Mrows, Hd);
}

// Round 6
// 2673.645 us; speedup vs baseline: 1.4514x; 1.0128x over previous
//
#include <hip/hip_runtime.h>
#include <cstdint>
#include <cstddef>

typedef float    float4v __attribute__((ext_vector_type(4)));
typedef _Float16 f16x4   __attribute__((ext_vector_type(4)));
typedef _Float16 f16x8   __attribute__((ext_vector_type(8)));
typedef unsigned long long u64;
struct u64p { u64 a, b; };

#define DI __device__ __forceinline__

static const int Bsz = 64, Tlen = 2048, Hd = 128, G4 = 512;  // 4H=512
static const int HSTR = 144;   // H row stride (f16): 0 bank conflicts, validated R7
static const int RING = 256;   // ring length (steps); lag bounds << 32 granules
static const int YSTR = 136;   // helper LDS row stride (f16)

DI float sigf_fast(float x) {
    float e = __builtin_amdgcn_exp2f(-1.442695041f * x);
    return __builtin_amdgcn_rcpf(1.f + e);
}
DI float tanhf_fast(float x) {
    float e = __builtin_amdgcn_exp2f(-2.885390082f * x);
    return 2.f * __builtin_amdgcn_rcpf(1.f + e) - 1.f;
}

// LDS-only barrier: no vmcnt drain (validated R5, -24%).
DI void lds_barrier() {
    asm volatile("s_waitcnt lgkmcnt(0)\n\ts_barrier" ::: "memory");
}

// Pin a 128-bit fragment in VGPRs (forbids weight rematerialization; R8).
DI void pin(f16x8& v) {
    float4v t = __builtin_bit_cast(float4v, v);
    asm volatile("" : "+v"(t));
    v = __builtin_bit_cast(f16x8, t);
}

// load 8 consecutive f32, convert to f16x8
DI f16x8 cvt8(const float* p) {
    float4v u = *(const float4v*)p;
    float4v w = *(const float4v*)(p + 4);
    f16x8 o;
    o[0] = (_Float16)u[0]; o[1] = (_Float16)u[1]; o[2] = (_Float16)u[2]; o[3] = (_Float16)u[3];
    o[4] = (_Float16)w[0]; o[5] = (_Float16)w[1]; o[6] = (_Float16)w[2]; o[7] = (_Float16)w[3];
    return o;
}

DI u64 ald64(const void* pp) {
    return __hip_atomic_load((const u64*)pp, __ATOMIC_RELAXED, __HIP_MEMORY_SCOPE_AGENT);
}
DI void ast16(void* pp, unsigned short v) {
    __hip_atomic_store((unsigned short*)pp, v, __ATOMIC_RELAXED, __HIP_MEMORY_SCOPE_AGENT);
}
DI unsigned int aldu32(const unsigned int* pp) {
    return __hip_atomic_load(pp, __ATOMIC_RELAXED, __HIP_MEMORY_SCOPE_AGENT);
}
DI void astu32(unsigned int* pp, unsigned int v) {
    __hip_atomic_store(pp, v, __ATOMIC_RELAXED, __HIP_MEMORY_SCOPE_AGENT);
}

// ---------------------------------------------------------------------------
// R14: fully-fused 4-role pipeline, one kernel per phase (no boundary GEMMs).
//   role 0 (WG  0-15): producer recurrence (R13 body). Phase A reads the xp
//                      ring X1 (from xph), polling prog3 once per granule.
//   role 1 (WG 16-31): consumer recurrence (R13 body). Phase B additionally
//                      publishes y1 (agent u16) + prog4 granule release.
//   role 2 (WG 32-47): Wih-helper (R13 verbatim): XP2 = Wih_c @ y0, ring X2.
//   role 3 (WG 48-63): phase A: xph  = x @ Wx^T (PERM) -> ring X1, prog3;
//                              lap-gated on producer progress (ring safety).
//                      phase B: out  = y1 @ oW^T + ob -> d_out (f32), polls
//                              prog4. Replaces the final GEMM dispatch.
// Handshakes (all validated pattern: granule release + counted vmcnt):
//   xph ->(prog3) prod ->(prog) Wih-helper ->(prog2) cons ->(prog4) out
//   back-gate: xph waits prog >= 8(g-32) before overwriting ring slots.
// Acyclic -> deadlock-free; 64 WGs/phase <= 256 CUs -> co-resident.
// ---------------------------------------------------------------------------
template <bool P_HAS_XP, bool P_INIT, bool C_INIT, bool R3_OUT>
__global__ __launch_bounds__(512, 1) void lstm_fused4(
    const float* __restrict__ Up, const float* __restrict__ bip, const float* __restrict__ bhp,
    const float* __restrict__ php, const float* __restrict__ pcp,
    float* __restrict__ fhp, float* __restrict__ fcp,
    const float* __restrict__ Wc, const float* __restrict__ Uc,
    const float* __restrict__ bic, const float* __restrict__ bhc,
    const float* __restrict__ phc, const float* __restrict__ pcc,
    float* __restrict__ fhc, float* __restrict__ fcc,
    const float* __restrict__ Wx, const float* __restrict__ xin,   // xph (phase A)
    const float* __restrict__ oW, const float* __restrict__ ob,    // out (phase B)
    float* __restrict__ outp,
    _Float16* __restrict__ PB,          // y0 ring  [64][RING][128] f16
    _Float16* __restrict__ X2,          // XP2 ring [64][RING][512] f16 (PERM)
    _Float16* __restrict__ X1,          // xp ring  [64][RING][512] f16 (PERM)
    _Float16* __restrict__ Y1,          // y1 full  [64][T][128] f16 (phase B)
    unsigned int* __restrict__ prog,  unsigned int* __restrict__ prog2,
    unsigned int* __restrict__ prog3, unsigned int* __restrict__ prog4, int T)
{
    const int tid  = threadIdx.x;
    const int lane = tid & 63, w = tid >> 6;
    const int col  = lane & 15, quad = lane >> 4;
    const int b    = col & 3, s = col >> 2;
    const int role = blockIdx.x >> 4;            // 0 prod, 1 cons, 2 Wih, 3 xph/out
    const int p    = blockIdx.x & 15;
    const int bglob = p * 4 + b;
    const int j    = w * 16 + s * 4 + quad;
    const int NG   = T >> 3;                     // T % 8 == 0

    __shared__ alignas(16) _Float16 Hl[2 * 4 * HSTR];
    __shared__ alignas(16) _Float16 Ylh[32 * YSTR];   // helper granule stage

    unsigned int* pr  = prog  + p * 16;   // 64B stride
    unsigned int* pr2 = prog2 + p * 16;
    unsigned int* pr3 = P_HAS_XP ? prog3 + p * 16 : nullptr;
    unsigned int* pr4 = R3_OUT   ? prog4 + p * 16 : nullptr;

    if (role == 0) {
        // ================= producer (R13 body; xp from X1 ring) ===========
        f16x8 af[4][4];
#pragma unroll
        for (int mt = 0; mt < 4; mt++) {
            int urow = (col & 3) * 128 + (w * 16 + mt * 4 + (col >> 2));
            const float* ur = Up + (size_t)urow * 128;
#pragma unroll
            for (int kc = 0; kc < 4; kc++) af[mt][kc] = cvt8(ur + kc * 32 + quad * 8);
        }
#pragma unroll
        for (int mt = 0; mt < 4; mt++)
#pragma unroll
            for (int kc = 0; kc < 4; kc++) pin(af[mt][kc]);

        float bq[4];
#pragma unroll
        for (int q = 0; q < 4; q++) bq[q] = bip[q * 128 + j] + bhp[q * 128 + j];

        float c = 0.f, hv = 0.f;
        if (P_INIT) {
            c  = pcp[(size_t)bglob * 128 + j];
            hv = php[(size_t)bglob * 128 + j];
        }
        Hl[b * HSTR + j] = (_Float16)hv;
        __syncthreads();

        const _Float16* x1b = P_HAS_XP ? X1 + (size_t)bglob * RING * 512 + 4 * j : nullptr;
        unsigned short* pbp = (unsigned short*)PB + (size_t)bglob * RING * 128 + j;

        if constexpr (P_HAS_XP) {
            // pre-poll: granule-0 prefetches reach xp index 8 -> xph granules
            // 0,1 done -> prog3 >= 16.
            if (tid == 511) {
                unsigned int need = 16u; if (need > (unsigned int)T) need = (unsigned int)T;
                unsigned int psn = aldu32(pr3);
                while (psn < need) { __builtin_amdgcn_s_sleep(8); psn = aldu32(pr3); }
            }
            __syncthreads();
        }
        f16x4 xp = {};
        if (P_HAS_XP) xp = __builtin_bit_cast(f16x4, ald64(x1b));   // xp(0)

        int cur = 0;
        for (int g = 0; g < NG; g++) {
#pragma unroll
            for (int k = 0; k < 8; k++) {
                const int t = g * 8 + k;
                f16x4 xpn = {};
                if (P_HAS_XP)   // t=T-1 reads slot 0 (stale, unused, in-bounds)
                    xpn = __builtin_bit_cast(f16x4, ald64(x1b + (size_t)((t + 1) & (RING - 1)) * 512));

                const _Float16* Hc = Hl + cur * (4 * HSTR);
                f16x8 bf[4];
#pragma unroll
                for (int kc = 0; kc < 4; kc++)
                    bf[kc] = *(const f16x8*)(Hc + b * HSTR + kc * 32 + quad * 8);

                float4v acc[4] = {};
#pragma unroll
                for (int kc = 0; kc < 4; kc++)
#pragma unroll
                    for (int mt = 0; mt < 4; mt++)
                        acc[mt] = __builtin_amdgcn_mfma_f32_16x16x32_f16(af[mt][kc], bf[kc], acc[mt], 0, 0, 0);

                float4v t0 = (s & 1) ? acc[1] : acc[0];
                float4v t1 = (s & 1) ? acc[3] : acc[2];
                float4v gg = (s & 2) ? t1 : t0;

                float g0 = gg[0] + bq[0], g1 = gg[1] + bq[1], g2 = gg[2] + bq[2], g3 = gg[3] + bq[3];
                if (P_HAS_XP) { g0 += (float)xp[0]; g1 += (float)xp[1]; g2 += (float)xp[2]; g3 += (float)xp[3]; }
                float iv = sigf_fast(g0), fv = sigf_fast(g1);
                float gv = tanhf_fast(g2), ov = sigf_fast(g3);
                c  = fv * c + iv * gv;
                hv = ov * tanhf_fast(c);

                _Float16 hf = (_Float16)hv;
                Hl[(cur ^ 1) * (4 * HSTR) + b * HSTR + j] = hf;
                ast16(pbp + (size_t)(t & (RING - 1)) * 128,
                      __builtin_bit_cast(unsigned short, hf));

                lds_barrier();
                xp = xpn;
                cur ^= 1;
            }
            // granule release: only newest {xpload, ystore} outstanding.
            if constexpr (P_HAS_XP) asm volatile("s_waitcnt vmcnt(2)" ::: "memory");
            else                    asm volatile("s_waitcnt vmcnt(1)" ::: "memory");
            if (tid == 0) astu32(pr, (unsigned int)(g * 8 + 7));
            if constexpr (P_HAS_XP) {
                // guarantee granule g+1's prefetches (xp idx <= 8(g+1)+8):
                // need prog3 >= 8(g+1)+9 -> next multiple of 8 = 8(g+1)+16.
                if (tid == 511 && g + 1 < NG) {
                    unsigned int need = (unsigned int)(8 * (g + 1) + 16);
                    if (need > (unsigned int)T) need = (unsigned int)T;
                    unsigned int psn = aldu32(pr3);
                    while (psn < need) { __builtin_amdgcn_s_sleep(2); psn = aldu32(pr3); }
                }
                lds_barrier();   // handoff before next granule's prefetches
            }
        }

        asm volatile("s_waitcnt vmcnt(0)" ::: "memory");
        __syncthreads();
        if (tid == 0) astu32(pr, (unsigned int)T);

        fhp[(size_t)bglob * 128 + j] = hv;
        fcp[(size_t)bglob * 128 + j] = c;
    } else if (role == 1) {
        // ================= consumer (R13 body; + y1 publish if R3_OUT) ====
        f16x8 afH[4][4];
#pragma unroll
        for (int mt = 0; mt < 4; mt++) {
            int urow = (col & 3) * 128 + (w * 16 + mt * 4 + (col >> 2));
            const float* ur = Uc + (size_t)urow * 128;
#pragma unroll
            for (int kc = 0; kc < 4; kc++) afH[mt][kc] = cvt8(ur + kc * 32 + quad * 8);
        }
#pragma unroll
        for (int mt = 0; mt < 4; mt++)
#pragma unroll
            for (int kc = 0; kc < 4; kc++) pin(afH[mt][kc]);

        float bq[4];
#pragma unroll
        for (int q = 0; q < 4; q++) bq[q] = bic[q * 128 + j] + bhc[q * 128 + j];

        float c = 0.f, hv = 0.f;
        if (C_INIT) {
            c  = pcc[(size_t)bglob * 128 + j];
            hv = phc[(size_t)bglob * 128 + j];
        }
        Hl[b * HSTR + j] = (_Float16)hv;

        if (tid == 511) {
            unsigned int need = 9u; if (need > (unsigned int)T) need = (unsigned int)T;
            unsigned int psn = aldu32(pr2);
            while (psn < need) { __builtin_amdgcn_s_sleep(8); psn = aldu32(pr2); }
        }
        __syncthreads();

        const _Float16* x2b = X2 + (size_t)bglob * RING * 512 + 4 * j;
        unsigned short* y1p = R3_OUT ? (unsigned short*)Y1 + (size_t)bglob * T * 128 + j : nullptr;
        f16x4 xp = __builtin_bit_cast(f16x4, ald64(x2b));   // xp2(0)

        int cur = 0;
        for (int g = 0; g < NG; g++) {
#pragma unroll
            for (int k = 0; k < 8; k++) {
                const int t = g * 8 + k;
                const int slot = (t + 1) & (RING - 1);
                f16x4 xpn = __builtin_bit_cast(f16x4, ald64(x2b + (size_t)slot * 512));

                const _Float16* Hc = Hl + cur * (4 * HSTR);
                f16x8 bf[4];
#pragma unroll
                for (int kc = 0; kc < 4; kc++)
                    bf[kc] = *(const f16x8*)(Hc + b * HSTR + kc * 32 + quad * 8);

                float4v acc[4] = {};
#pragma unroll
                for (int kc = 0; kc < 4; kc++)
#pragma unroll
                    for (int mt = 0; mt < 4; mt++)
                        acc[mt] = __builtin_amdgcn_mfma_f32_16x16x32_f16(afH[mt][kc], bf[kc], acc[mt], 0, 0, 0);

                float4v t0 = (s & 1) ? acc[1] : acc[0];
                float4v t1 = (s & 1) ? acc[3] : acc[2];
                float4v gg = (s & 2) ? t1 : t0;

                float g0 = gg[0] + bq[0] + (float)xp[0], g1 = gg[1] + bq[1] + (float)xp[1];
                float g2 = gg[2] + bq[2] + (float)xp[2], g3 = gg[3] + bq[3] + (float)xp[3];
                float iv = sigf_fast(g0), fv = sigf_fast(g1);
                float gv = tanhf_fast(g2), ov = sigf_fast(g3);
                c  = fv * c + iv * gv;
                hv = ov * tanhf_fast(c);

                _Float16 hf = (_Float16)hv;
                Hl[(cur ^ 1) * (4 * HSTR) + b * HSTR + j] = hf;
                if constexpr (R3_OUT)
                    ast16(y1p + (size_t)t * 128, __builtin_bit_cast(unsigned short, hf));

                lds_barrier();
                xp = xpn;
                cur ^= 1;
            }
            if constexpr (R3_OUT) {
                // y1(<=8g+6) ACKed (newest {xpload, y1store} may remain).
                asm volatile("s_waitcnt vmcnt(2)" ::: "memory");
                if (tid == 0) astu32(pr4, (unsigned int)(g * 8 + 7));
            }
            if (tid == 511 && g + 1 < NG) {
                unsigned int need = (unsigned int)(8 * (g + 1) + 9);
                if (need > (unsigned int)T) need = (unsigned int)T;
                unsigned int psn = aldu32(pr2);
                while (psn < need) { __builtin_amdgcn_s_sleep(2); psn = aldu32(pr2); }
            }
            lds_barrier();
        }

        if constexpr (R3_OUT) {
            asm volatile("s_waitcnt vmcnt(0)" ::: "memory");
            __syncthreads();
            if (tid == 0) astu32(pr4, (unsigned int)T);
        }
        fhc[(size_t)bglob * 128 + j] = hv;
        fcc[(size_t)bglob * 128 + j] = c;
    } else if (role == 2) {
        // ================= Wih-helper (R13 verbatim) ======================
        f16x8 bw[4][4];
#pragma unroll
        for (int nt = 0; nt < 4; nt++) {
            int n = (w * 4 + nt) * 16 + col;
            int wrow = (n & 3) * 128 + (n >> 2);
            const float* Wr = Wc + (size_t)wrow * 128;
#pragma unroll
            for (int kc = 0; kc < 4; kc++) bw[nt][kc] = cvt8(Wr + kc * 32 + quad * 8);
        }
#pragma unroll
        for (int nt = 0; nt < 4; nt++)
#pragma unroll
            for (int kc = 0; kc < 4; kc++) pin(bw[nt][kc]);

        const int lrow = tid >> 4, lchunk = tid & 15;
        const int lb = lrow & 3, ltr = lrow >> 2;

        for (int g = 0; g < NG; g++) {
            if (tid == 0) {
                unsigned int need = (unsigned int)(g * 8 + 8);
                unsigned int psn = aldu32(pr);
                while (psn < need) { __builtin_amdgcn_s_sleep(4); psn = aldu32(pr); }
            }
            __syncthreads();
            {
                int slot = (g * 8 + ltr) & (RING - 1);
                const char* srcp = (const char*)(PB + ((size_t)(p * 4 + lb) * RING + slot) * 128 + lchunk * 8);
                u64 a0 = ald64(srcp);
                u64 a1 = ald64(srcp + 8);
                char* dst = (char*)&Ylh[lrow * YSTR + lchunk * 8];
                *(u64*)dst = a0;
                *(u64*)(dst + 8) = a1;
            }
            lds_barrier();

            float4v acc[2][4] = {};
#pragma unroll
            for (int kc = 0; kc < 4; kc++) {
                f16x8 a0 = *(const f16x8*)&Ylh[col * YSTR + kc * 32 + quad * 8];
                f16x8 a1 = *(const f16x8*)&Ylh[(16 + col) * YSTR + kc * 32 + quad * 8];
#pragma unroll
                for (int nt = 0; nt < 4; nt++) {
                    acc[0][nt] = __builtin_amdgcn_mfma_f32_16x16x32_f16(a0, bw[nt][kc], acc[0][nt], 0, 0, 0);
                    acc[1][nt] = __builtin_amdgcn_mfma_f32_16x16x32_f16(a1, bw[nt][kc], acc[1][nt], 0, 0, 0);
                }
            }
#pragma unroll
            for (int mt = 0; mt < 2; mt++)
#pragma unroll
                for (int nt = 0; nt < 4; nt++) {
                    int n = (w * 4 + nt) * 16 + col;
#pragma unroll
                    for (int r = 0; r < 4; r++) {
                        int m = mt * 16 + quad * 4 + r;
                        int bb = m & 3, trow = m >> 2;
                        int slot = (g * 8 + trow) & (RING - 1);
                        _Float16 hval = (_Float16)acc[mt][nt][r];
                        ast16(X2 + ((size_t)(p * 4 + bb) * RING + slot) * 512 + n,
                              __builtin_bit_cast(unsigned short, hval));
                    }
                }
            asm volatile("s_waitcnt vmcnt(0)" ::: "memory");
            __syncthreads();
            if (tid == 0) astu32(pr2, (unsigned int)(g * 8 + 8));
        }
    } else if constexpr (!R3_OUT) {
        // ================= xph: XP(t) = x[t] @ Wx^T (PERM) -> X1 ring =====
        f16x8 bw[4][4];
#pragma unroll
        for (int nt = 0; nt < 4; nt++) {
            int n = (w * 4 + nt) * 16 + col;
            int wrow = (n & 3) * 128 + (n >> 2);
            const float* Wr = Wx + (size_t)wrow * 128;
#pragma unroll
            for (int kc = 0; kc < 4; kc++) bw[nt][kc] = cvt8(Wr + kc * 32 + quad * 8);
        }
#pragma unroll
        for (int nt = 0; nt < 4; nt++)
#pragma unroll
            for (int kc = 0; kc < 4; kc++) pin(bw[nt][kc]);

        const int lrow = tid >> 4, lchunk = tid & 15;
        const int lb = lrow & 3, ltr = lrow >> 2;
        const float* xsrc = xin + (size_t)(p * 4 + lb) * T * 128 + lchunk * 8;

        for (int g = 0; g < NG; g++) {
            // lap-gate: don't overwrite xp slots the producer hasn't read.
            if (g >= 32 && tid == 0) {
                unsigned int need = (unsigned int)(8 * (g - 32));
                unsigned int psn = aldu32(pr);
                while (psn < need) { __builtin_amdgcn_s_sleep(4); psn = aldu32(pr); }
            }
            __syncthreads();
            {   // stage x granule, f32 -> f16
                f16x8 xv = cvt8(xsrc + (size_t)(g * 8 + ltr) * 128);
                u64p w2 = __builtin_bit_cast(u64p, xv);
                char* dst = (char*)&Ylh[lrow * YSTR + lchunk * 8];
                *(u64*)dst = w2.a;
                *(u64*)(dst + 8) = w2.b;
            }
            lds_barrier();

            float4v acc[2][4] = {};
#pragma unroll
            for (int kc = 0; kc < 4; kc++) {
                f16x8 a0 = *(const f16x8*)&Ylh[col * YSTR + kc * 32 + quad * 8];
                f16x8 a1 = *(const f16x8*)&Ylh[(16 + col) * YSTR + kc * 32 + quad * 8];
#pragma unroll
                for (int nt = 0; nt < 4; nt++) {
                    acc[0][nt] = __builtin_amdgcn_mfma_f32_16x16x32_f16(a0, bw[nt][kc], acc[0][nt], 0, 0, 0);
                    acc[1][nt] = __builtin_amdgcn_mfma_f32_16x16x32_f16(a1, bw[nt][kc], acc[1][nt], 0, 0, 0);
                }
            }
#pragma unroll
            for (int mt = 0; mt < 2; mt++)
#pragma unroll
                for (int nt = 0; nt < 4; nt++) {
                    int n = (w * 4 + nt) * 16 + col;
#pragma unroll
                    for (int r = 0; r < 4; r++) {
                        int m = mt * 16 + quad * 4 + r;
                        int bb = m & 3, trow = m >> 2;
                        int slot = (g * 8 + trow) & (RING - 1);
                        _Float16 hval = (_Float16)acc[mt][nt][r];
                        ast16(X1 + ((size_t)(p * 4 + bb) * RING + slot) * 512 + n,
                              __builtin_bit_cast(unsigned short, hval));
                    }
                }
            asm volatile("s_waitcnt vmcnt(0)" ::: "memory");
            __syncthreads();
            if (tid == 0) astu32(pr3, (unsigned int)(g * 8 + 8));
        }
    } else {
        // ================= out: d_out = y1 @ oW^T + ob (f32) ==============
        const int n = w * 16 + col;
        f16x8 bo[4];
#pragma unroll
        for (int kc = 0; kc < 4; kc++) bo[kc] = cvt8(oW + (size_t)n * 128 + kc * 32 + quad * 8);
#pragma unroll
        for (int kc = 0; kc < 4; kc++) pin(bo[kc]);
        const float bv = ob[n];

        const int lrow = tid >> 4, lchunk = tid & 15;
        const int lb = lrow & 3, ltr = lrow >> 2;

        for (int g = 0; g < NG; g++) {
            if (tid == 0) {
                unsigned int need = (unsigned int)(g * 8 + 8);
                unsigned int psn = aldu32(pr4);
                while (psn < need) { __builtin_amdgcn_s_sleep(4); psn = aldu32(pr4); }
            }
            __syncthreads();   // also fences prior granule's Ylh reads
            {
                const char* srcp = (const char*)(Y1 + ((size_t)(p * 4 + lb) * T + g * 8 + ltr) * 128 + lchunk * 8);
                u64 a0 = ald64(srcp);
                u64 a1 = ald64(srcp + 8);
                char* dst = (char*)&Ylh[lrow * YSTR + lchunk * 8];
                *(u64*)dst = a0;
                *(u64*)(dst + 8) = a1;
            }
            lds_barrier();

            float4v acc[2] = {};
#pragma unroll
            for (int kc = 0; kc < 4; kc++) {
                f16x8 a0 = *(const f16x8*)&Ylh[col * YSTR + kc * 32 + quad * 8];
                f16x8 a1 = *(const f16x8*)&Ylh[(16 + col) * YSTR + kc * 32 + quad * 8];
                acc[0] = __builtin_amdgcn_mfma_f32_16x16x32_f16(a0, bo[kc], acc[0], 0, 0, 0);
                acc[1] = __builtin_amdgcn_mfma_f32_16x16x32_f16(a1, bo[kc], acc[1], 0, 0, 0);
            }
#pragma unroll
            for (int mt = 0; mt < 2; mt++)
#pragma unroll
                for (int r = 0; r < 4; r++) {
                    int m = mt * 16 + quad * 4 + r;
                    int bb = m & 3, trow = m >> 2;
                    outp[((size_t)(p * 4 + bb) * T + g * 8 + trow) * 128 + n] = acc[mt][r] + bv;
                }
        }
    }
}

// ---------------------------------------------------------------------------
// Host: memset + 2 fused launches (was 5 dispatches).
//   ws map: X1 [0,16M) | X2A [16M,32M) | PBA [32M,36M) | X2B [36M,52M) |
//           PBB [52M,56M) | Y1 [56M,88M) | finals [88M,+128K) | prog (+8K)
// ---------------------------------------------------------------------------
extern "C" void kernel_launch(void* const* d_in, const int* in_sizes, int n_in,
                              void* d_out, int out_size, void* d_ws, size_t ws_size,
                              hipStream_t stream)
{
    const float* x    = (const float*)d_in[0];
    const float* eW0  = (const float*)d_in[1];
    const float* eU0  = (const float*)d_in[2];
    const float* eb0i = (const float*)d_in[3];
    const float* eb0h = (const float*)d_in[4];
    const float* eW1  = (const float*)d_in[5];
    const float* eU1  = (const float*)d_in[6];
    const float* eb1i = (const float*)d_in[7];
    const float* eb1h = (const float*)d_in[8];
    const float* dU0  = (const float*)d_in[10];
    const float* db0i = (const float*)d_in[11];
    const float* db0h = (const float*)d_in[12];
    const float* dW1  = (const float*)d_in[13];
    const float* dU1  = (const float*)d_in[14];
    const float* db1i = (const float*)d_in[15];
    const float* db1h = (const float*)d_in[16];
    const float* oW   = (const float*)d_in[17];
    const float* ob   = (const float*)d_in[18];

    char* ws = (char*)d_ws;
    _Float16* X1  = (_Float16*)(ws);
    _Float16* X2A = (_Float16*)(ws + (16u << 20));
    _Float16* PBA = (_Float16*)(ws + (32u << 20));
    _Float16* X2B = (_Float16*)(ws + (36u << 20));
    _Float16* PBB = (_Float16*)(ws + (52u << 20));
    _Float16* Y1  = (_Float16*)(ws + (56u << 20));
    float*    fh0 = (float*)(ws + (88u << 20));
    float*    fc0 = fh0 + Bsz * Hd;
    float*    fh1 = fc0 + Bsz * Hd;
    float*    fc1 = fh1 + Bsz * Hd;
    unsigned int* pg = (unsigned int*)(ws + (88u << 20) + (1u << 17));
    unsigned int* progA  = pg + 0 * 256;
    unsigned int* prog2A = pg + 1 * 256;
    unsigned int* prog3A = pg + 2 * 256;
    unsigned int* progB  = pg + 3 * 256;
    unsigned int* prog2B = pg + 4 * 256;
    unsigned int* prog4B = pg + 5 * 256;

    // zero progress counters (graph-safe, re-zeroed every replay)
    hipMemsetAsync((void*)pg, 0, 8192, stream);

    // phase A: encL0 (prod, xp from xph) || Wih-helper(eW1) || encL1 (cons) || xph(eW0)
    lstm_fused4<true, false, false, false><<<dim3(64), dim3(512), 0, stream>>>(
        eU0, eb0i, eb0h, (const float*)nullptr, (const float*)nullptr, fh0, fc0,
        eW1, eU1, eb1i, eb1h, (const float*)nullptr, (const float*)nullptr, fh1, fc1,
        eW0, x,
        (const float*)nullptr, (const float*)nullptr, (float*)nullptr,
        PBA, X2A, X1, (_Float16*)nullptr,
        progA, prog2A, prog3A, (unsigned int*)nullptr, Tlen);

    // phase B: decL0 (prod, no xp, init enc finals) || Wih-helper(dW1) ||
    //          decL1 (cons, init, publishes y1) || out(oW, ob -> d_out)
    lstm_fused4<false, true, true, true><<<dim3(64), dim3(512), 0, stream>>>(
        dU0, db0i, db0h, fh0, fc0, fh0, fc0,
        dW1, dU1, db1i, db1h, fh1, fc1, fh1, fc1,
        (const float*)nullptr, (const float*)nullptr,
        oW, ob, (float*)d_out,
        PBB, X2B, (_Float16*)nullptr, Y1,
        progB, prog2B, (unsigned int*)nullptr, prog4B, Tlen);
}

// Round 7
// 2576.075 us; speedup vs baseline: 1.5064x; 1.0379x over previous
//
#include <hip/hip_runtime.h>
#include <cstdint>
#include <cstddef>

typedef float    float4v __attribute__((ext_vector_type(4)));
typedef _Float16 f16x4   __attribute__((ext_vector_type(4)));
typedef _Float16 f16x8   __attribute__((ext_vector_type(8)));
typedef unsigned long long u64;
struct u64p { u64 a, b; };

#define DI __device__ __forceinline__

static const int Bsz = 64, Tlen = 2048, Hd = 128, G4 = 512;  // 4H=512
static const int HSTR = 144;   // H row stride (f16): 0 bank conflicts, validated R7
static const int RING = 256;   // ring length (steps); lag bounds << 32 granules
static const int YSTR = 136;   // helper LDS row stride (f16)

DI float sigf_fast(float x) {
    float e = __builtin_amdgcn_exp2f(-1.442695041f * x);
    return __builtin_amdgcn_rcpf(1.f + e);
}
DI float tanhf_fast(float x) {
    float e = __builtin_amdgcn_exp2f(-2.885390082f * x);
    return 2.f * __builtin_amdgcn_rcpf(1.f + e) - 1.f;
}

// LDS-only barrier: no vmcnt drain (validated R5, -24%).
DI void lds_barrier() {
    asm volatile("s_waitcnt lgkmcnt(0)\n\ts_barrier" ::: "memory");
}

// Pin a 128-bit fragment in VGPRs (forbids weight rematerialization; R8).
DI void pin(f16x8& v) {
    float4v t = __builtin_bit_cast(float4v, v);
    asm volatile("" : "+v"(t));
    v = __builtin_bit_cast(f16x8, t);
}

// load 8 consecutive f32, convert to f16x8
DI f16x8 cvt8(const float* p) {
    float4v u = *(const float4v*)p;
    float4v w = *(const float4v*)(p + 4);
    f16x8 o;
    o[0] = (_Float16)u[0]; o[1] = (_Float16)u[1]; o[2] = (_Float16)u[2]; o[3] = (_Float16)u[3];
    o[4] = (_Float16)w[0]; o[5] = (_Float16)w[1]; o[6] = (_Float16)w[2]; o[7] = (_Float16)w[3];
    return o;
}

// pack 4 f32 -> 4 f16 -> u64 (for vectorized agent stores)
DI u64 pack4(float4v a) {
    f16x4 h;
    h[0] = (_Float16)a[0]; h[1] = (_Float16)a[1];
    h[2] = (_Float16)a[2]; h[3] = (_Float16)a[3];
    return __builtin_bit_cast(u64, h);
}

DI u64 ald64(const void* pp) {
    return __hip_atomic_load((const u64*)pp, __ATOMIC_RELAXED, __HIP_MEMORY_SCOPE_AGENT);
}
DI void ast64(void* pp, u64 v) {
    __hip_atomic_store((u64*)pp, v, __ATOMIC_RELAXED, __HIP_MEMORY_SCOPE_AGENT);
}
DI void ast16(void* pp, unsigned short v) {
    __hip_atomic_store((unsigned short*)pp, v, __ATOMIC_RELAXED, __HIP_MEMORY_SCOPE_AGENT);
}
DI unsigned int aldu32(const unsigned int* pp) {
    return __hip_atomic_load(pp, __ATOMIC_RELAXED, __HIP_MEMORY_SCOPE_AGENT);
}
DI void astu32(unsigned int* pp, unsigned int v) {
    __hip_atomic_store(pp, v, __ATOMIC_RELAXED, __HIP_MEMORY_SCOPE_AGENT);
}

// ---------------------------------------------------------------------------
// R15: R14 4-role pipeline, integration overhead removed.
// R14 post-mortem: phases inflated (+107 A, +267 B). Causes addressed here:
//   (1) Y1 was a 32MB streaming buffer: consumer's granule-end vmcnt(2)
//       waited on HBM-bound store ACKs (~1us x 256 granules). Y1 is now a
//       4MB LLC-resident RING; 'out' publishes consumed-progress prog5;
//       consumer back-gates at g>=32 (never blocks: out lags ~2 granules).
//   (2) granule-end [vmcnt -> release -> poll] merged into step 7 BEFORE its
//       barrier: 8 barriers/granule (was 9). Semantics identical.
//   (3) helper/xph/out use SWAPPED-operand MFMA: mfma(W, y) puts n in the
//       acc r-index -> stores vectorize to 8 u64 (helpers) / 2 float4 (out)
//       per thread (was 32 / 8 scalar). Fragment READ addresses unchanged.
// Handshakes (identical numerology to R13/R14):
//   xph ->(prog3) prod ->(prog) Wih ->(prog2) cons ->(prog4) out ->(prog5) cons
// ---------------------------------------------------------------------------
template <bool P_HAS_XP, bool P_INIT, bool C_INIT, bool R3_OUT>
__global__ __launch_bounds__(512, 1) void lstm_fused5(
    const float* __restrict__ Up, const float* __restrict__ bip, const float* __restrict__ bhp,
    const float* __restrict__ php, const float* __restrict__ pcp,
    float* __restrict__ fhp, float* __restrict__ fcp,
    const float* __restrict__ Wc, const float* __restrict__ Uc,
    const float* __restrict__ bic, const float* __restrict__ bhc,
    const float* __restrict__ phc, const float* __restrict__ pcc,
    float* __restrict__ fhc, float* __restrict__ fcc,
    const float* __restrict__ Wx, const float* __restrict__ xin,   // xph (phase A)
    const float* __restrict__ oW, const float* __restrict__ ob,    // out (phase B)
    float* __restrict__ outp,
    _Float16* __restrict__ PB,          // y0 ring  [64][RING][128] f16
    _Float16* __restrict__ X2,          // XP2 ring [64][RING][512] f16 (PERM)
    _Float16* __restrict__ X1,          // xp ring  [64][RING][512] f16 (PERM)
    _Float16* __restrict__ Y1,          // y1 ring  [64][RING][128] f16 (phase B)
    unsigned int* __restrict__ prog,  unsigned int* __restrict__ prog2,
    unsigned int* __restrict__ prog3, unsigned int* __restrict__ prog4,
    unsigned int* __restrict__ prog5, int T)
{
    const int tid  = threadIdx.x;
    const int lane = tid & 63, w = tid >> 6;
    const int col  = lane & 15, quad = lane >> 4;
    const int b    = col & 3, s = col >> 2;
    const int role = blockIdx.x >> 4;            // 0 prod, 1 cons, 2 Wih, 3 xph/out
    const int p    = blockIdx.x & 15;
    const int bglob = p * 4 + b;
    const int j    = w * 16 + s * 4 + quad;
    const int NG   = T >> 3;                     // T % 8 == 0

    __shared__ alignas(16) _Float16 Hl[2 * 4 * HSTR];
    __shared__ alignas(16) _Float16 Ylh[32 * YSTR];   // helper granule stage

    unsigned int* pr  = prog  + p * 16;   // 64B stride
    unsigned int* pr2 = prog2 + p * 16;
    unsigned int* pr3 = P_HAS_XP ? prog3 + p * 16 : nullptr;
    unsigned int* pr4 = R3_OUT   ? prog4 + p * 16 : nullptr;
    unsigned int* pr5 = R3_OUT   ? prog5 + p * 16 : nullptr;

    if (role == 0) {
        // ================= producer (merged granule-end) ==================
        f16x8 af[4][4];
#pragma unroll
        for (int mt = 0; mt < 4; mt++) {
            int urow = (col & 3) * 128 + (w * 16 + mt * 4 + (col >> 2));
            const float* ur = Up + (size_t)urow * 128;
#pragma unroll
            for (int kc = 0; kc < 4; kc++) af[mt][kc] = cvt8(ur + kc * 32 + quad * 8);
        }
#pragma unroll
        for (int mt = 0; mt < 4; mt++)
#pragma unroll
            for (int kc = 0; kc < 4; kc++) pin(af[mt][kc]);

        float bq[4];
#pragma unroll
        for (int q = 0; q < 4; q++) bq[q] = bip[q * 128 + j] + bhp[q * 128 + j];

        float c = 0.f, hv = 0.f;
        if (P_INIT) {
            c  = pcp[(size_t)bglob * 128 + j];
            hv = php[(size_t)bglob * 128 + j];
        }
        Hl[b * HSTR + j] = (_Float16)hv;
        __syncthreads();

        const _Float16* x1b = P_HAS_XP ? X1 + (size_t)bglob * RING * 512 + 4 * j : nullptr;
        unsigned short* pbp = (unsigned short*)PB + (size_t)bglob * RING * 128 + j;

        if constexpr (P_HAS_XP) {
            // pre-poll: granule-0 prefetches reach xp index 8 -> prog3 >= 16
            if (tid == 511) {
                unsigned int need = 16u; if (need > (unsigned int)T) need = (unsigned int)T;
                unsigned int psn = aldu32(pr3);
                while (psn < need) { __builtin_amdgcn_s_sleep(8); psn = aldu32(pr3); }
            }
            __syncthreads();
        }
        f16x4 xp = {};
        if (P_HAS_XP) xp = __builtin_bit_cast(f16x4, ald64(x1b));   // xp(0)

        int cur = 0;
        for (int g = 0; g < NG; g++) {
#pragma unroll
            for (int k = 0; k < 8; k++) {
                const int t = g * 8 + k;
                f16x4 xpn = {};
                if (P_HAS_XP)   // t=T-1 reads slot 0 (stale, unused, in-bounds)
                    xpn = __builtin_bit_cast(f16x4, ald64(x1b + (size_t)((t + 1) & (RING - 1)) * 512));

                const _Float16* Hc = Hl + cur * (4 * HSTR);
                f16x8 bf[4];
#pragma unroll
                for (int kc = 0; kc < 4; kc++)
                    bf[kc] = *(const f16x8*)(Hc + b * HSTR + kc * 32 + quad * 8);

                float4v acc[4] = {};
#pragma unroll
                for (int kc = 0; kc < 4; kc++)
#pragma unroll
                    for (int mt = 0; mt < 4; mt++)
                        acc[mt] = __builtin_amdgcn_mfma_f32_16x16x32_f16(af[mt][kc], bf[kc], acc[mt], 0, 0, 0);

                float4v t0 = (s & 1) ? acc[1] : acc[0];
                float4v t1 = (s & 1) ? acc[3] : acc[2];
                float4v gg = (s & 2) ? t1 : t0;

                float g0 = gg[0] + bq[0], g1 = gg[1] + bq[1], g2 = gg[2] + bq[2], g3 = gg[3] + bq[3];
                if (P_HAS_XP) { g0 += (float)xp[0]; g1 += (float)xp[1]; g2 += (float)xp[2]; g3 += (float)xp[3]; }
                float iv = sigf_fast(g0), fv = sigf_fast(g1);
                float gv = tanhf_fast(g2), ov = sigf_fast(g3);
                c  = fv * c + iv * gv;
                hv = ov * tanhf_fast(c);

                _Float16 hf = (_Float16)hv;
                Hl[(cur ^ 1) * (4 * HSTR) + b * HSTR + j] = hf;
                ast16(pbp + (size_t)(t & (RING - 1)) * 128,
                      __builtin_bit_cast(unsigned short, hf));

                if (k == 7) {
                    // merged granule-end: release + poll BEFORE step-7 barrier
                    if constexpr (P_HAS_XP) asm volatile("s_waitcnt vmcnt(2)" ::: "memory");
                    else                    asm volatile("s_waitcnt vmcnt(1)" ::: "memory");
                    if (tid == 0) astu32(pr, (unsigned int)(g * 8 + 7));
                    if constexpr (P_HAS_XP) {
                        if (tid == 511 && g + 1 < NG) {
                            unsigned int need = (unsigned int)(8 * (g + 1) + 16);
                            if (need > (unsigned int)T) need = (unsigned int)T;
                            unsigned int psn = aldu32(pr3);
                            while (psn < need) { __builtin_amdgcn_s_sleep(2); psn = aldu32(pr3); }
                        }
                    }
                }
                lds_barrier();
                xp = xpn;
                cur ^= 1;
            }
        }

        asm volatile("s_waitcnt vmcnt(0)" ::: "memory");
        __syncthreads();
        if (tid == 0) astu32(pr, (unsigned int)T);

        fhp[(size_t)bglob * 128 + j] = hv;
        fcp[(size_t)bglob * 128 + j] = c;
    } else if (role == 1) {
        // ================= consumer (ring y1 publish; merged end) =========
        f16x8 afH[4][4];
#pragma unroll
        for (int mt = 0; mt < 4; mt++) {
            int urow = (col & 3) * 128 + (w * 16 + mt * 4 + (col >> 2));
            const float* ur = Uc + (size_t)urow * 128;
#pragma unroll
            for (int kc = 0; kc < 4; kc++) afH[mt][kc] = cvt8(ur + kc * 32 + quad * 8);
        }
#pragma unroll
        for (int mt = 0; mt < 4; mt++)
#pragma unroll
            for (int kc = 0; kc < 4; kc++) pin(afH[mt][kc]);

        float bq[4];
#pragma unroll
        for (int q = 0; q < 4; q++) bq[q] = bic[q * 128 + j] + bhc[q * 128 + j];

        float c = 0.f, hv = 0.f;
        if (C_INIT) {
            c  = pcc[(size_t)bglob * 128 + j];
            hv = phc[(size_t)bglob * 128 + j];
        }
        Hl[b * HSTR + j] = (_Float16)hv;

        if (tid == 511) {
            unsigned int need = 9u; if (need > (unsigned int)T) need = (unsigned int)T;
            unsigned int psn = aldu32(pr2);
            while (psn < need) { __builtin_amdgcn_s_sleep(8); psn = aldu32(pr2); }
        }
        __syncthreads();

        const _Float16* x2b = X2 + (size_t)bglob * RING * 512 + 4 * j;
        unsigned short* y1p = R3_OUT ? (unsigned short*)Y1 + (size_t)bglob * RING * 128 + j : nullptr;
        f16x4 xp = __builtin_bit_cast(f16x4, ald64(x2b));   // xp2(0)

        int cur = 0;
        for (int g = 0; g < NG; g++) {
#pragma unroll
            for (int k = 0; k < 8; k++) {
                const int t = g * 8 + k;
                const int slot = (t + 1) & (RING - 1);
                f16x4 xpn = __builtin_bit_cast(f16x4, ald64(x2b + (size_t)slot * 512));

                const _Float16* Hc = Hl + cur * (4 * HSTR);
                f16x8 bf[4];
#pragma unroll
                for (int kc = 0; kc < 4; kc++)
                    bf[kc] = *(const f16x8*)(Hc + b * HSTR + kc * 32 + quad * 8);

                float4v acc[4] = {};
#pragma unroll
                for (int kc = 0; kc < 4; kc++)
#pragma unroll
                    for (int mt = 0; mt < 4; mt++)
                        acc[mt] = __builtin_amdgcn_mfma_f32_16x16x32_f16(afH[mt][kc], bf[kc], acc[mt], 0, 0, 0);

                float4v t0 = (s & 1) ? acc[1] : acc[0];
                float4v t1 = (s & 1) ? acc[3] : acc[2];
                float4v gg = (s & 2) ? t1 : t0;

                float g0 = gg[0] + bq[0] + (float)xp[0], g1 = gg[1] + bq[1] + (float)xp[1];
                float g2 = gg[2] + bq[2] + (float)xp[2], g3 = gg[3] + bq[3] + (float)xp[3];
                float iv = sigf_fast(g0), fv = sigf_fast(g1);
                float gv = tanhf_fast(g2), ov = sigf_fast(g3);
                c  = fv * c + iv * gv;
                hv = ov * tanhf_fast(c);

                _Float16 hf = (_Float16)hv;
                Hl[(cur ^ 1) * (4 * HSTR) + b * HSTR + j] = hf;
                if constexpr (R3_OUT)
                    ast16(y1p + (size_t)(t & (RING - 1)) * 128,
                          __builtin_bit_cast(unsigned short, hf));

                if (k == 7) {
                    if constexpr (R3_OUT) {
                        // y1(<=8g+6) ACKed (newest {xp2load, y1store} remain)
                        asm volatile("s_waitcnt vmcnt(2)" ::: "memory");
                        if (tid == 0) astu32(pr4, (unsigned int)(g * 8 + 7));
                    }
                    if (tid == 511 && g + 1 < NG) {
                        unsigned int need = (unsigned int)(8 * (g + 1) + 9);
                        if (need > (unsigned int)T) need = (unsigned int)T;
                        unsigned int psn = aldu32(pr2);
                        while (psn < need) { __builtin_amdgcn_s_sleep(2); psn = aldu32(pr2); }
                        if constexpr (R3_OUT) {
                            // ring back-gate: slots for granule g+1 reused from
                            // granule g+1-32; out must have staged it.
                            if (g + 1 >= 32) {
                                unsigned int need5 = (unsigned int)(8 * (g + 1 - 32) + 8);
                                unsigned int p5 = aldu32(pr5);
                                while (p5 < need5) { __builtin_amdgcn_s_sleep(2); p5 = aldu32(pr5); }
                            }
                        }
                    }
                }
                lds_barrier();
                xp = xpn;
                cur ^= 1;
            }
        }

        if constexpr (R3_OUT) {
            asm volatile("s_waitcnt vmcnt(0)" ::: "memory");
            __syncthreads();
            if (tid == 0) astu32(pr4, (unsigned int)T);
        }
        fhc[(size_t)bglob * 128 + j] = hv;
        fcc[(size_t)bglob * 128 + j] = c;
    } else if (role == 2) {
        // ========== Wih-helper: XP2 = Wih_c @ y0 (swapped-operand) ========
        f16x8 bw[4][4];
#pragma unroll
        for (int nt = 0; nt < 4; nt++) {
            int n = (w * 4 + nt) * 16 + col;
            int wrow = (n & 3) * 128 + (n >> 2);
            const float* Wr = Wc + (size_t)wrow * 128;
#pragma unroll
            for (int kc = 0; kc < 4; kc++) bw[nt][kc] = cvt8(Wr + kc * 32 + quad * 8);
        }
#pragma unroll
        for (int nt = 0; nt < 4; nt++)
#pragma unroll
            for (int kc = 0; kc < 4; kc++) pin(bw[nt][kc]);

        const int lrow = tid >> 4, lchunk = tid & 15;
        const int lb = lrow & 3, ltr = lrow >> 2;

        for (int g = 0; g < NG; g++) {
            if (tid == 0) {
                unsigned int need = (unsigned int)(g * 8 + 8);
                unsigned int psn = aldu32(pr);
                while (psn < need) { __builtin_amdgcn_s_sleep(4); psn = aldu32(pr); }
            }
            __syncthreads();
            {
                int slot = (g * 8 + ltr) & (RING - 1);
                const char* srcp = (const char*)(PB + ((size_t)(p * 4 + lb) * RING + slot) * 128 + lchunk * 8);
                u64 a0 = ald64(srcp);
                u64 a1 = ald64(srcp + 8);
                char* dst = (char*)&Ylh[lrow * YSTR + lchunk * 8];
                *(u64*)dst = a0;
                *(u64*)(dst + 8) = a1;
            }
            lds_barrier();

            // swapped: A = W rows (n), B = y cols (m). C[n][m].
            float4v acc[2][4] = {};
#pragma unroll
            for (int kc = 0; kc < 4; kc++) {
                f16x8 y0 = *(const f16x8*)&Ylh[col * YSTR + kc * 32 + quad * 8];
                f16x8 y1t = *(const f16x8*)&Ylh[(16 + col) * YSTR + kc * 32 + quad * 8];
#pragma unroll
                for (int nt = 0; nt < 4; nt++) {
                    acc[0][nt] = __builtin_amdgcn_mfma_f32_16x16x32_f16(bw[nt][kc], y0,  acc[0][nt], 0, 0, 0);
                    acc[1][nt] = __builtin_amdgcn_mfma_f32_16x16x32_f16(bw[nt][kc], y1t, acc[1][nt], 0, 0, 0);
                }
            }
            // stores: thread holds n = (w*4+nt)*16 + quad*4 + r (r contiguous)
            // for m = mt*16 + col -> one u64 per (mt,nt): 8 stores (was 32).
            {
                const int bb = col & 3;
#pragma unroll
                for (int mt = 0; mt < 2; mt++) {
                    int trow = mt * 4 + (col >> 2);
                    int slot = (g * 8 + trow) & (RING - 1);
                    _Float16* dst = X2 + ((size_t)(p * 4 + bb) * RING + slot) * 512 + (w * 4) * 16 + quad * 4;
#pragma unroll
                    for (int nt = 0; nt < 4; nt++)
                        ast64(dst + nt * 16, pack4(acc[mt][nt]));
                }
            }
            asm volatile("s_waitcnt vmcnt(0)" ::: "memory");
            __syncthreads();
            if (tid == 0) astu32(pr2, (unsigned int)(g * 8 + 8));
        }
    } else if constexpr (!R3_OUT) {
        // ========== xph: XP = x @ Wx^T (PERM, swapped-operand) -> X1 ======
        f16x8 bw[4][4];
#pragma unroll
        for (int nt = 0; nt < 4; nt++) {
            int n = (w * 4 + nt) * 16 + col;
            int wrow = (n & 3) * 128 + (n >> 2);
            const float* Wr = Wx + (size_t)wrow * 128;
#pragma unroll
            for (int kc = 0; kc < 4; kc++) bw[nt][kc] = cvt8(Wr + kc * 32 + quad * 8);
        }
#pragma unroll
        for (int nt = 0; nt < 4; nt++)
#pragma unroll
            for (int kc = 0; kc < 4; kc++) pin(bw[nt][kc]);

        const int lrow = tid >> 4, lchunk = tid & 15;
        const int lb = lrow & 3, ltr = lrow >> 2;
        const float* xsrc = xin + (size_t)(p * 4 + lb) * T * 128 + lchunk * 8;

        for (int g = 0; g < NG; g++) {
            // lap-gate: don't overwrite xp slots the producer hasn't read.
            if (g >= 32 && tid == 0) {
                unsigned int need = (unsigned int)(8 * (g - 32));
                unsigned int psn = aldu32(pr);
                while (psn < need) { __builtin_amdgcn_s_sleep(4); psn = aldu32(pr); }
            }
            __syncthreads();
            {   // stage x granule, f32 -> f16
                f16x8 xv = cvt8(xsrc + (size_t)(g * 8 + ltr) * 128);
                u64p w2 = __builtin_bit_cast(u64p, xv);
                char* dst = (char*)&Ylh[lrow * YSTR + lchunk * 8];
                *(u64*)dst = w2.a;
                *(u64*)(dst + 8) = w2.b;
            }
            lds_barrier();

            float4v acc[2][4] = {};
#pragma unroll
            for (int kc = 0; kc < 4; kc++) {
                f16x8 y0 = *(const f16x8*)&Ylh[col * YSTR + kc * 32 + quad * 8];
                f16x8 y1t = *(const f16x8*)&Ylh[(16 + col) * YSTR + kc * 32 + quad * 8];
#pragma unroll
                for (int nt = 0; nt < 4; nt++) {
                    acc[0][nt] = __builtin_amdgcn_mfma_f32_16x16x32_f16(bw[nt][kc], y0,  acc[0][nt], 0, 0, 0);
                    acc[1][nt] = __builtin_amdgcn_mfma_f32_16x16x32_f16(bw[nt][kc], y1t, acc[1][nt], 0, 0, 0);
                }
            }
            {
                const int bb = col & 3;
#pragma unroll
                for (int mt = 0; mt < 2; mt++) {
                    int trow = mt * 4 + (col >> 2);
                    int slot = (g * 8 + trow) & (RING - 1);
                    _Float16* dst = X1 + ((size_t)(p * 4 + bb) * RING + slot) * 512 + (w * 4) * 16 + quad * 4;
#pragma unroll
                    for (int nt = 0; nt < 4; nt++)
                        ast64(dst + nt * 16, pack4(acc[mt][nt]));
                }
            }
            asm volatile("s_waitcnt vmcnt(0)" ::: "memory");
            __syncthreads();
            if (tid == 0) astu32(pr3, (unsigned int)(g * 8 + 8));
        }
    } else {
        // ========== out: d_out = y1 @ oW^T + ob (swapped, float4 stores) ===
        f16x8 bo[4];
#pragma unroll
        for (int kc = 0; kc < 4; kc++) bo[kc] = cvt8(oW + (size_t)(w * 16 + col) * 128 + kc * 32 + quad * 8);
#pragma unroll
        for (int kc = 0; kc < 4; kc++) pin(bo[kc]);
        // bias along n = w*16 + quad*4 + r (r contiguous)
        float4v bv4 = *(const float4v*)(ob + w * 16 + quad * 4);

        const int lrow = tid >> 4, lchunk = tid & 15;
        const int lb = lrow & 3, ltr = lrow >> 2;

        for (int g = 0; g < NG; g++) {
            if (tid == 0) {
                unsigned int need = (unsigned int)(g * 8 + 8);
                unsigned int psn = aldu32(pr4);
                while (psn < need) { __builtin_amdgcn_s_sleep(4); psn = aldu32(pr4); }
            }
            __syncthreads();   // also fences prior granule's Ylh reads
            {
                int slot = (g * 8 + ltr) & (RING - 1);
                const char* srcp = (const char*)(Y1 + ((size_t)(p * 4 + lb) * RING + slot) * 128 + lchunk * 8);
                u64 a0 = ald64(srcp);
                u64 a1 = ald64(srcp + 8);
                char* dst = (char*)&Ylh[lrow * YSTR + lchunk * 8];
                *(u64*)dst = a0;
                *(u64*)(dst + 8) = a1;
            }
            lds_barrier();
            // release consumed-progress: granule g's ring slots fully staged.
            if (tid == 0) astu32(pr5, (unsigned int)(g * 8 + 8));

            float4v acc[2] = {};
#pragma unroll
            for (int kc = 0; kc < 4; kc++) {
                f16x8 y0 = *(const f16x8*)&Ylh[col * YSTR + kc * 32 + quad * 8];
                f16x8 y1t = *(const f16x8*)&Ylh[(16 + col) * YSTR + kc * 32 + quad * 8];
                acc[0] = __builtin_amdgcn_mfma_f32_16x16x32_f16(bo[kc], y0,  acc[0], 0, 0, 0);
                acc[1] = __builtin_amdgcn_mfma_f32_16x16x32_f16(bo[kc], y1t, acc[1], 0, 0, 0);
            }
            {
                const int bb = col & 3;
#pragma unroll
                for (int mt = 0; mt < 2; mt++) {
                    int trow = mt * 4 + (col >> 2);
                    float4v v = acc[mt];
                    v[0] += bv4[0]; v[1] += bv4[1]; v[2] += bv4[2]; v[3] += bv4[3];
                    *(float4v*)(outp + ((size_t)(p * 4 + bb) * T + g * 8 + trow) * 128 + w * 16 + quad * 4) = v;
                }
            }
        }
    }
}

// ---------------------------------------------------------------------------
// Host: memset + 2 fused launches.
//   ws map: X1 [0,16M) | X2A [16,32M) | PBA [32,36M) | X2B [36,52M) |
//           PBB [52,56M) | Y1R [56,60M) | finals [88M,+128K) | prog (+8K)
// ---------------------------------------------------------------------------
extern "C" void kernel_launch(void* const* d_in, const int* in_sizes, int n_in,
                              void* d_out, int out_size, void* d_ws, size_t ws_size,
                              hipStream_t stream)
{
    const float* x    = (const float*)d_in[0];
    const float* eW0  = (const float*)d_in[1];
    const float* eU0  = (const float*)d_in[2];
    const float* eb0i = (const float*)d_in[3];
    const float* eb0h = (const float*)d_in[4];
    const float* eW1  = (const float*)d_in[5];
    const float* eU1  = (const float*)d_in[6];
    const float* eb1i = (const float*)d_in[7];
    const float* eb1h = (const float*)d_in[8];
    const float* dU0  = (const float*)d_in[10];
    const float* db0i = (const float*)d_in[11];
    const float* db0h = (const float*)d_in[12];
    const float* dW1  = (const float*)d_in[13];
    const float* dU1  = (const float*)d_in[14];
    const float* db1i = (const float*)d_in[15];
    const float* db1h = (const float*)d_in[16];
    const float* oW   = (const float*)d_in[17];
    const float* ob   = (const float*)d_in[18];

    char* ws = (char*)d_ws;
    _Float16* X1  = (_Float16*)(ws);
    _Float16* X2A = (_Float16*)(ws + (16u << 20));
    _Float16* PBA = (_Float16*)(ws + (32u << 20));
    _Float16* X2B = (_Float16*)(ws + (36u << 20));
    _Float16* PBB = (_Float16*)(ws + (52u << 20));
    _Float16* Y1R = (_Float16*)(ws + (56u << 20));
    float*    fh0 = (float*)(ws + (88u << 20));
    float*    fc0 = fh0 + Bsz * Hd;
    float*    fh1 = fc0 + Bsz * Hd;
    float*    fc1 = fh1 + Bsz * Hd;
    unsigned int* pg = (unsigned int*)(ws + (88u << 20) + (1u << 17));
    unsigned int* progA  = pg + 0 * 256;
    unsigned int* prog2A = pg + 1 * 256;
    unsigned int* prog3A = pg + 2 * 256;
    unsigned int* progB  = pg + 3 * 256;
    unsigned int* prog2B = pg + 4 * 256;
    unsigned int* prog4B = pg + 5 * 256;
    unsigned int* prog5B = pg + 6 * 256;

    // zero progress counters (graph-safe, re-zeroed every replay)
    hipMemsetAsync((void*)pg, 0, 8192, stream);

    // phase A: encL0 (prod, xp from xph) || Wih-helper(eW1) || encL1 (cons) || xph(eW0)
    lstm_fused5<true, false, false, false><<<dim3(64), dim3(512), 0, stream>>>(
        eU0, eb0i, eb0h, (const float*)nullptr, (const float*)nullptr, fh0, fc0,
        eW1, eU1, eb1i, eb1h, (const float*)nullptr, (const float*)nullptr, fh1, fc1,
        eW0, x,
        (const float*)nullptr, (const float*)nullptr, (float*)nullptr,
        PBA, X2A, X1, (_Float16*)nullptr,
        progA, prog2A, prog3A, (unsigned int*)nullptr, (unsigned int*)nullptr, Tlen);

    // phase B: decL0 (prod, no xp, init enc finals) || Wih-helper(dW1) ||
    //          decL1 (cons, init, publishes y1 ring) || out(oW, ob -> d_out)
    lstm_fused5<false, true, true, true><<<dim3(64), dim3(512), 0, stream>>>(
        dU0, db0i, db0h, fh0, fc0, fh0, fc0,
        dW1, dU1, db1i, db1h, fh1, fc1, fh1, fc1,
        (const float*)nullptr, (const float*)nullptr,
        oW, ob, (float*)d_out,
        PBB, X2B, (_Float16*)nullptr, Y1R,
        progB, prog2B, (unsigned int*)nullptr, prog4B, prog5B, Tlen);
}

// Round 8
// 2400.256 us; speedup vs baseline: 1.6167x; 1.0733x over previous
//
#include <hip/hip_runtime.h>
#include <cstdint>
#include <cstddef>

typedef float    float4v __attribute__((ext_vector_type(4)));
typedef _Float16 f16x4   __attribute__((ext_vector_type(4)));
typedef _Float16 f16x8   __attribute__((ext_vector_type(8)));
typedef unsigned long long u64;
struct u64p { u64 a, b; };

#define DI __device__ __forceinline__

static const int Bsz = 64, Tlen = 2048, Hd = 128;
static const int HSTR = 144;   // H row stride (f16): 0 bank conflicts (R7)
static const int RING = 256;   // ring length (steps); lag bounds << 32 granules
static const int YSTR = 136;   // helper LDS row stride (f16)

DI float sigf_fast(float x) {
    float e = __builtin_amdgcn_exp2f(-1.442695041f * x);
    return __builtin_amdgcn_rcpf(1.f + e);
}
DI float tanhf_fast(float x) {
    float e = __builtin_amdgcn_exp2f(-2.885390082f * x);
    return 2.f * __builtin_amdgcn_rcpf(1.f + e) - 1.f;
}

// LDS-only barrier: no vmcnt drain (validated R5).
DI void lds_barrier() {
    asm volatile("s_waitcnt lgkmcnt(0)\n\ts_barrier" ::: "memory");
}

// Pin a 128-bit fragment in VGPRs (forbids weight rematerialization; R8).
DI void pin(f16x8& v) {
    float4v t = __builtin_bit_cast(float4v, v);
    asm volatile("" : "+v"(t));
    v = __builtin_bit_cast(f16x8, t);
}

// load 8 consecutive f32, convert to f16x8
DI f16x8 cvt8(const float* p) {
    float4v u = *(const float4v*)p;
    float4v w = *(const float4v*)(p + 4);
    f16x8 o;
    o[0] = (_Float16)u[0]; o[1] = (_Float16)u[1]; o[2] = (_Float16)u[2]; o[3] = (_Float16)u[3];
    o[4] = (_Float16)w[0]; o[5] = (_Float16)w[1]; o[6] = (_Float16)w[2]; o[7] = (_Float16)w[3];
    return o;
}

// pack 4 f32 -> 4 f16 -> u64 (vectorized agent stores)
DI u64 pack4(float4v a) {
    f16x4 h;
    h[0] = (_Float16)a[0]; h[1] = (_Float16)a[1];
    h[2] = (_Float16)a[2]; h[3] = (_Float16)a[3];
    return __builtin_bit_cast(u64, h);
}

DI u64 ald64(const void* pp) {
    return __hip_atomic_load((const u64*)pp, __ATOMIC_RELAXED, __HIP_MEMORY_SCOPE_AGENT);
}
DI void ast64(void* pp, u64 v) {
    __hip_atomic_store((u64*)pp, v, __ATOMIC_RELAXED, __HIP_MEMORY_SCOPE_AGENT);
}
DI void ast16(void* pp, unsigned short v) {
    __hip_atomic_store((unsigned short*)pp, v, __ATOMIC_RELAXED, __HIP_MEMORY_SCOPE_AGENT);
}
DI unsigned int aldu32(const unsigned int* pp) {
    return __hip_atomic_load(pp, __ATOMIC_RELAXED, __HIP_MEMORY_SCOPE_AGENT);
}
DI void astu32(unsigned int* pp, unsigned int v) {
    __hip_atomic_store(pp, v, __ATOMIC_RELAXED, __HIP_MEMORY_SCOPE_AGENT);
}

// ---------------------------------------------------------------------------
// R16: single mega-kernel. Every role runs BOTH phases (2T steps), weights
// switch at g==NG. State (h,c) carries across the phase boundary IN REGISTERS
// (decL0 init = encL0 final; decL1 init = encL1 final) -- no fh/fc globals,
// no phase-B relaunch/reload/ramp, no inter-dispatch drain.
//   role 0 (WG  0-15): producer. enc: encL0 (xp from X1 ring); dec: decL0
//                      (no xp). Publishes y0 -> PB ring + prog, 0..2T.
//   role 1 (WG 16-31): consumer. enc: encL1; dec: decL1 (+y1 ring + prog4).
//                      xp2 from X2 ring flows CONTINUOUSLY across boundary.
//   role 2 (WG 32-47): Wih-helper. eW1 then dW1. PB -> X2 ring, prog2.
//   role 3 (WG 48-63): xph: XP = x @ eW0^T -> X1 ring, prog3. Exits at NG.
//   role 4 (WG 64-79): out: d_out = y1 @ oW^T + ob. Runs g = NG..2NG.
// In-flight polling (R10 trick) at the three critical-path poll sites:
// sample the counter at granule TOP (tid511), check at k==7 -> zero stall
// when the upstream role is ahead (it always is in steady state).
// Handshake numerology identical to R13-R15, t extended to 2T.
// ---------------------------------------------------------------------------
__global__ __launch_bounds__(512, 1) void lstm_mega(
    const float* __restrict__ eU0, const float* __restrict__ eb0i, const float* __restrict__ eb0h,
    const float* __restrict__ dU0, const float* __restrict__ db0i, const float* __restrict__ db0h,
    const float* __restrict__ eU1, const float* __restrict__ eb1i, const float* __restrict__ eb1h,
    const float* __restrict__ dU1, const float* __restrict__ db1i, const float* __restrict__ db1h,
    const float* __restrict__ eW1, const float* __restrict__ dW1,
    const float* __restrict__ eW0, const float* __restrict__ xin,
    const float* __restrict__ oW,  const float* __restrict__ ob,
    float* __restrict__ outp,
    _Float16* __restrict__ PB,          // y0 ring  [64][RING][128] f16
    _Float16* __restrict__ X2,          // xp2 ring [64][RING][512] f16 (PERM)
    _Float16* __restrict__ X1,          // xp  ring [64][RING][512] f16 (PERM)
    _Float16* __restrict__ Y1,          // y1  ring [64][RING][128] f16
    unsigned int* __restrict__ prog,  unsigned int* __restrict__ prog2,
    unsigned int* __restrict__ prog3, unsigned int* __restrict__ prog4,
    unsigned int* __restrict__ prog5, int T)
{
    const int tid  = threadIdx.x;
    const int lane = tid & 63, w = tid >> 6;
    const int col  = lane & 15, quad = lane >> 4;
    const int b    = col & 3, s = col >> 2;
    const int role = blockIdx.x >> 4;        // 0 prod, 1 cons, 2 Wih, 3 xph, 4 out
    const int p    = blockIdx.x & 15;
    const int bglob = p * 4 + b;
    const int j    = w * 16 + s * 4 + quad;
    const int NG   = T >> 3;                 // T % 8 == 0 (T=2048)
    const int NG2  = NG * 2;
    const unsigned int T2 = (unsigned int)(2 * T);

    __shared__ alignas(16) _Float16 Hl[2 * 4 * HSTR];
    __shared__ alignas(16) _Float16 Ylh[32 * YSTR];   // helper granule stage

    unsigned int* pr  = prog  + p * 16;   // 64B stride
    unsigned int* pr2 = prog2 + p * 16;
    unsigned int* pr3 = prog3 + p * 16;
    unsigned int* pr4 = prog4 + p * 16;
    unsigned int* pr5 = prog5 + p * 16;

    if (role == 0) {
        // ================= producer: encL0 then decL0 =====================
        f16x8 af[4][4];
        float bq[4];
#pragma unroll
        for (int mt = 0; mt < 4; mt++) {
            int urow = (col & 3) * 128 + (w * 16 + mt * 4 + (col >> 2));
            const float* ur = eU0 + (size_t)urow * 128;
#pragma unroll
            for (int kc = 0; kc < 4; kc++) { af[mt][kc] = cvt8(ur + kc * 32 + quad * 8); pin(af[mt][kc]); }
        }
#pragma unroll
        for (int q = 0; q < 4; q++) bq[q] = eb0i[q * 128 + j] + eb0h[q * 128 + j];

        float c = 0.f, hv = 0.f;
        Hl[b * HSTR + j] = (_Float16)0.f;
        __syncthreads();

        const _Float16* x1b = X1 + (size_t)bglob * RING * 512 + 4 * j;
        unsigned short* pbp = (unsigned short*)PB + (size_t)bglob * RING * 128 + j;

        // pre-poll: granule-0 prefetches reach xp index 8 -> prog3 >= 16
        if (tid == 511) {
            unsigned int need = 16u; if (need > (unsigned int)T) need = (unsigned int)T;
            unsigned int psn = aldu32(pr3);
            while (psn < need) { __builtin_amdgcn_s_sleep(8); psn = aldu32(pr3); }
        }
        __syncthreads();
        f16x4 xp = __builtin_bit_cast(f16x4, ald64(x1b));   // xp(0)

        int cur = 0;
        unsigned int pf3 = 0, ps3 = 0;
        for (int g = 0; g < NG2; g++) {
            if (g == NG) {
                // phase switch: decL0 weights/biases; state (c,hv) continues.
#pragma unroll
                for (int mt = 0; mt < 4; mt++) {
                    int urow = (col & 3) * 128 + (w * 16 + mt * 4 + (col >> 2));
                    const float* ur = dU0 + (size_t)urow * 128;
#pragma unroll
                    for (int kc = 0; kc < 4; kc++) { af[mt][kc] = cvt8(ur + kc * 32 + quad * 8); pin(af[mt][kc]); }
                }
#pragma unroll
                for (int q = 0; q < 4; q++) bq[q] = db0i[q * 128 + j] + db0h[q * 128 + j];
            }
            if (g < NG) {
                // in-flight prog3 sample (checked at k==7)
                if (tid == 511 && g + 1 < NG) pf3 = aldu32(pr3);
#pragma unroll
                for (int k = 0; k < 8; k++) {
                    const int t = g * 8 + k;
                    f16x4 xpn = __builtin_bit_cast(f16x4,
                        ald64(x1b + (size_t)((t + 1) & (RING - 1)) * 512));

                    const _Float16* Hc = Hl + cur * (4 * HSTR);
                    f16x8 bf[4];
#pragma unroll
                    for (int kc = 0; kc < 4; kc++)
                        bf[kc] = *(const f16x8*)(Hc + b * HSTR + kc * 32 + quad * 8);

                    float4v acc[4] = {};
#pragma unroll
                    for (int kc = 0; kc < 4; kc++)
#pragma unroll
                        for (int mt = 0; mt < 4; mt++)
                            acc[mt] = __builtin_amdgcn_mfma_f32_16x16x32_f16(af[mt][kc], bf[kc], acc[mt], 0, 0, 0);

                    float4v t0 = (s & 1) ? acc[1] : acc[0];
                    float4v t1 = (s & 1) ? acc[3] : acc[2];
                    float4v gg = (s & 2) ? t1 : t0;

                    float g0 = gg[0] + bq[0] + (float)xp[0], g1 = gg[1] + bq[1] + (float)xp[1];
                    float g2 = gg[2] + bq[2] + (float)xp[2], g3 = gg[3] + bq[3] + (float)xp[3];
                    float iv = sigf_fast(g0), fv = sigf_fast(g1);
                    float gv = tanhf_fast(g2), ov = sigf_fast(g3);
                    c  = fv * c + iv * gv;
                    hv = ov * tanhf_fast(c);

                    _Float16 hf = (_Float16)hv;
                    Hl[(cur ^ 1) * (4 * HSTR) + b * HSTR + j] = hf;
                    ast16(pbp + (size_t)(t & (RING - 1)) * 128,
                          __builtin_bit_cast(unsigned short, hf));

                    if (k == 7) {
                        // only newest {xpload, PBstore} outstanding -> y(<=8g+6) ACKed
                        asm volatile("s_waitcnt vmcnt(2)" ::: "memory");
                        if (tid == 0) astu32(pr, (unsigned int)(g * 8 + 7));
                        if (tid == 511 && g + 1 < NG) {
                            unsigned int need = (unsigned int)(8 * (g + 1) + 16);
                            if (need > (unsigned int)T) need = (unsigned int)T;
                            if (ps3 < pf3) ps3 = pf3;
                            while (ps3 < need) { __builtin_amdgcn_s_sleep(2); ps3 = aldu32(pr3); }
                        }
                    }
                    lds_barrier();
                    xp = xpn;
                    cur ^= 1;
                }
            } else {
#pragma unroll
                for (int k = 0; k < 8; k++) {
                    const int t = g * 8 + k;

                    const _Float16* Hc = Hl + cur * (4 * HSTR);
                    f16x8 bf[4];
#pragma unroll
                    for (int kc = 0; kc < 4; kc++)
                        bf[kc] = *(const f16x8*)(Hc + b * HSTR + kc * 32 + quad * 8);

                    float4v acc[4] = {};
#pragma unroll
                    for (int kc = 0; kc < 4; kc++)
#pragma unroll
                        for (int mt = 0; mt < 4; mt++)
                            acc[mt] = __builtin_amdgcn_mfma_f32_16x16x32_f16(af[mt][kc], bf[kc], acc[mt], 0, 0, 0);

                    float4v t0 = (s & 1) ? acc[1] : acc[0];
                    float4v t1 = (s & 1) ? acc[3] : acc[2];
                    float4v gg = (s & 2) ? t1 : t0;

                    float g0 = gg[0] + bq[0], g1 = gg[1] + bq[1];
                    float g2 = gg[2] + bq[2], g3 = gg[3] + bq[3];
                    float iv = sigf_fast(g0), fv = sigf_fast(g1);
                    float gv = tanhf_fast(g2), ov = sigf_fast(g3);
                    c  = fv * c + iv * gv;
                    hv = ov * tanhf_fast(c);

                    _Float16 hf = (_Float16)hv;
                    Hl[(cur ^ 1) * (4 * HSTR) + b * HSTR + j] = hf;
                    ast16(pbp + (size_t)(t & (RING - 1)) * 128,
                          __builtin_bit_cast(unsigned short, hf));

                    if (k == 7) {
                        asm volatile("s_waitcnt vmcnt(1)" ::: "memory");
                        if (tid == 0) astu32(pr, (unsigned int)(g * 8 + 7));
                    }
                    lds_barrier();
                    cur ^= 1;
                }
            }
        }
        asm volatile("s_waitcnt vmcnt(0)" ::: "memory");
        __syncthreads();
        if (tid == 0) astu32(pr, T2);
    } else if (role == 1) {
        // ================= consumer: encL1 then decL1 =====================
        f16x8 afH[4][4];
        float bq[4];
#pragma unroll
        for (int mt = 0; mt < 4; mt++) {
            int urow = (col & 3) * 128 + (w * 16 + mt * 4 + (col >> 2));
            const float* ur = eU1 + (size_t)urow * 128;
#pragma unroll
            for (int kc = 0; kc < 4; kc++) { afH[mt][kc] = cvt8(ur + kc * 32 + quad * 8); pin(afH[mt][kc]); }
        }
#pragma unroll
        for (int q = 0; q < 4; q++) bq[q] = eb1i[q * 128 + j] + eb1h[q * 128 + j];

        float c = 0.f, hv = 0.f;
        Hl[b * HSTR + j] = (_Float16)0.f;

        // pre-poll: granule-0 prefetches reach xp2 index 8 -> prog2 >= 9
        if (tid == 511) {
            unsigned int need = 9u; if (need > T2) need = T2;
            unsigned int psn = aldu32(pr2);
            while (psn < need) { __builtin_amdgcn_s_sleep(8); psn = aldu32(pr2); }
        }
        __syncthreads();

        const _Float16* x2b = X2 + (size_t)bglob * RING * 512 + 4 * j;
        unsigned short* y1p = (unsigned short*)Y1 + (size_t)bglob * RING * 128 + j;
        f16x4 xp = __builtin_bit_cast(f16x4, ald64(x2b));   // xp2(0)

        int cur = 0;
        unsigned int pf2 = 0, ps2 = 0, pf5 = 0, ps5 = 0;
        for (int g = 0; g < NG2; g++) {
            if (g == NG) {
                // phase switch: decL1 weights/biases; state continues.
#pragma unroll
                for (int mt = 0; mt < 4; mt++) {
                    int urow = (col & 3) * 128 + (w * 16 + mt * 4 + (col >> 2));
                    const float* ur = dU1 + (size_t)urow * 128;
#pragma unroll
                    for (int kc = 0; kc < 4; kc++) { afH[mt][kc] = cvt8(ur + kc * 32 + quad * 8); pin(afH[mt][kc]); }
                }
#pragma unroll
                for (int q = 0; q < 4; q++) bq[q] = db1i[q * 128 + j] + db1h[q * 128 + j];
            }
            // in-flight samples (checked at k==7)
            if (tid == 511) {
                if (g + 1 < NG2) pf2 = aldu32(pr2);
                if (g + 1 >= NG + 32 && g + 1 < NG2) pf5 = aldu32(pr5);
            }
            if (g < NG) {
#pragma unroll
                for (int k = 0; k < 8; k++) {
                    const int t = g * 8 + k;
                    f16x4 xpn = __builtin_bit_cast(f16x4,
                        ald64(x2b + (size_t)((t + 1) & (RING - 1)) * 512));

                    const _Float16* Hc = Hl + cur * (4 * HSTR);
                    f16x8 bf[4];
#pragma unroll
                    for (int kc = 0; kc < 4; kc++)
                        bf[kc] = *(const f16x8*)(Hc + b * HSTR + kc * 32 + quad * 8);

                    float4v acc[4] = {};
#pragma unroll
                    for (int kc = 0; kc < 4; kc++)
#pragma unroll
                        for (int mt = 0; mt < 4; mt++)
                            acc[mt] = __builtin_amdgcn_mfma_f32_16x16x32_f16(afH[mt][kc], bf[kc], acc[mt], 0, 0, 0);

                    float4v t0 = (s & 1) ? acc[1] : acc[0];
                    float4v t1 = (s & 1) ? acc[3] : acc[2];
                    float4v gg = (s & 2) ? t1 : t0;

                    float g0 = gg[0] + bq[0] + (float)xp[0], g1 = gg[1] + bq[1] + (float)xp[1];
                    float g2 = gg[2] + bq[2] + (float)xp[2], g3 = gg[3] + bq[3] + (float)xp[3];
                    float iv = sigf_fast(g0), fv = sigf_fast(g1);
                    float gv = tanhf_fast(g2), ov = sigf_fast(g3);
                    c  = fv * c + iv * gv;
                    hv = ov * tanhf_fast(c);

                    Hl[(cur ^ 1) * (4 * HSTR) + b * HSTR + j] = (_Float16)hv;

                    if (k == 7) {
                        if (tid == 511 && g + 1 < NG2) {
                            unsigned int need = (unsigned int)(8 * (g + 1) + 9);
                            if (need > T2) need = T2;
                            if (ps2 < pf2) ps2 = pf2;
                            while (ps2 < need) { __builtin_amdgcn_s_sleep(2); ps2 = aldu32(pr2); }
                        }
                    }
                    lds_barrier();
                    xp = xpn;
                    cur ^= 1;
                }
            } else {
#pragma unroll
                for (int k = 0; k < 8; k++) {
                    const int t = g * 8 + k;
                    f16x4 xpn = __builtin_bit_cast(f16x4,
                        ald64(x2b + (size_t)((t + 1) & (RING - 1)) * 512));

                    const _Float16* Hc = Hl + cur * (4 * HSTR);
                    f16x8 bf[4];
#pragma unroll
                    for (int kc = 0; kc < 4; kc++)
                        bf[kc] = *(const f16x8*)(Hc + b * HSTR + kc * 32 + quad * 8);

                    float4v acc[4] = {};
#pragma unroll
                    for (int kc = 0; kc < 4; kc++)
#pragma unroll
                        for (int mt = 0; mt < 4; mt++)
                            acc[mt] = __builtin_amdgcn_mfma_f32_16x16x32_f16(afH[mt][kc], bf[kc], acc[mt], 0, 0, 0);

                    float4v t0 = (s & 1) ? acc[1] : acc[0];
                    float4v t1 = (s & 1) ? acc[3] : acc[2];
                    float4v gg = (s & 2) ? t1 : t0;

                    float g0 = gg[0] + bq[0] + (float)xp[0], g1 = gg[1] + bq[1] + (float)xp[1];
                    float g2 = gg[2] + bq[2] + (float)xp[2], g3 = gg[3] + bq[3] + (float)xp[3];
                    float iv = sigf_fast(g0), fv = sigf_fast(g1);
                    float gv = tanhf_fast(g2), ov = sigf_fast(g3);
                    c  = fv * c + iv * gv;
                    hv = ov * tanhf_fast(c);

                    _Float16 hf = (_Float16)hv;
                    Hl[(cur ^ 1) * (4 * HSTR) + b * HSTR + j] = hf;
                    ast16(y1p + (size_t)(t & (RING - 1)) * 128,
                          __builtin_bit_cast(unsigned short, hf));

                    if (k == 7) {
                        // y1(<=8g+6) ACKed (newest {xp2load, y1store} remain)
                        asm volatile("s_waitcnt vmcnt(2)" ::: "memory");
                        if (tid == 0) astu32(pr4, (unsigned int)(g * 8 + 7));
                        if (tid == 511 && g + 1 < NG2) {
                            unsigned int need = (unsigned int)(8 * (g + 1) + 9);
                            if (need > T2) need = T2;
                            if (ps2 < pf2) ps2 = pf2;
                            while (ps2 < need) { __builtin_amdgcn_s_sleep(2); ps2 = aldu32(pr2); }
                            if (g + 1 >= NG + 32) {
                                // y1-ring back-gate: out must have staged g+1-32
                                unsigned int need5 = (unsigned int)(8 * (g + 1 - 32) + 8);
                                if (ps5 < pf5) ps5 = pf5;
                                while (ps5 < need5) { __builtin_amdgcn_s_sleep(2); ps5 = aldu32(pr5); }
                            }
                        }
                    }
                    lds_barrier();
                    xp = xpn;
                    cur ^= 1;
                }
            }
        }
        asm volatile("s_waitcnt vmcnt(0)" ::: "memory");
        __syncthreads();
        if (tid == 0) astu32(pr4, T2);
    } else if (role == 2) {
        // ========== Wih-helper: XP2 = W @ y0 (swapped-operand), 2T ========
        f16x8 bw[4][4];
#pragma unroll
        for (int nt = 0; nt < 4; nt++) {
            int n = (w * 4 + nt) * 16 + col;
            int wrow = (n & 3) * 128 + (n >> 2);
            const float* Wr = eW1 + (size_t)wrow * 128;
#pragma unroll
            for (int kc = 0; kc < 4; kc++) { bw[nt][kc] = cvt8(Wr + kc * 32 + quad * 8); pin(bw[nt][kc]); }
        }

        const int lrow = tid >> 4, lchunk = tid & 15;
        const int lb = lrow & 3, ltr = lrow >> 2;

        for (int g = 0; g < NG2; g++) {
            if (g == NG) {
#pragma unroll
                for (int nt = 0; nt < 4; nt++) {
                    int n = (w * 4 + nt) * 16 + col;
                    int wrow = (n & 3) * 128 + (n >> 2);
                    const float* Wr = dW1 + (size_t)wrow * 128;
#pragma unroll
                    for (int kc = 0; kc < 4; kc++) { bw[nt][kc] = cvt8(Wr + kc * 32 + quad * 8); pin(bw[nt][kc]); }
                }
            }
            if (tid == 0) {
                unsigned int need = (unsigned int)(g * 8 + 8);
                unsigned int psn = aldu32(pr);
                while (psn < need) { __builtin_amdgcn_s_sleep(4); psn = aldu32(pr); }
            }
            __syncthreads();
            {
                int slot = (g * 8 + ltr) & (RING - 1);
                const char* srcp = (const char*)(PB + ((size_t)(p * 4 + lb) * RING + slot) * 128 + lchunk * 8);
                u64 a0 = ald64(srcp);
                u64 a1 = ald64(srcp + 8);
                char* dst = (char*)&Ylh[lrow * YSTR + lchunk * 8];
                *(u64*)dst = a0;
                *(u64*)(dst + 8) = a1;
            }
            lds_barrier();

            float4v acc[2][4] = {};
#pragma unroll
            for (int kc = 0; kc < 4; kc++) {
                f16x8 y0 = *(const f16x8*)&Ylh[col * YSTR + kc * 32 + quad * 8];
                f16x8 y1t = *(const f16x8*)&Ylh[(16 + col) * YSTR + kc * 32 + quad * 8];
#pragma unroll
                for (int nt = 0; nt < 4; nt++) {
                    acc[0][nt] = __builtin_amdgcn_mfma_f32_16x16x32_f16(bw[nt][kc], y0,  acc[0][nt], 0, 0, 0);
                    acc[1][nt] = __builtin_amdgcn_mfma_f32_16x16x32_f16(bw[nt][kc], y1t, acc[1][nt], 0, 0, 0);
                }
            }
            {
                const int bb = col & 3;
#pragma unroll
                for (int mt = 0; mt < 2; mt++) {
                    int trow = mt * 4 + (col >> 2);
                    int slot = (g * 8 + trow) & (RING - 1);
                    _Float16* dst = X2 + ((size_t)(p * 4 + bb) * RING + slot) * 512 + (w * 4) * 16 + quad * 4;
#pragma unroll
                    for (int nt = 0; nt < 4; nt++)
                        ast64(dst + nt * 16, pack4(acc[mt][nt]));
                }
            }
            asm volatile("s_waitcnt vmcnt(0)" ::: "memory");
            __syncthreads();
            if (tid == 0) astu32(pr2, (unsigned int)(g * 8 + 8));
        }
    } else if (role == 3) {
        // ========== xph: XP = x @ eW0^T (PERM, swapped) -> X1, exits at NG =
        f16x8 bw[4][4];
#pragma unroll
        for (int nt = 0; nt < 4; nt++) {
            int n = (w * 4 + nt) * 16 + col;
            int wrow = (n & 3) * 128 + (n >> 2);
            const float* Wr = eW0 + (size_t)wrow * 128;
#pragma unroll
            for (int kc = 0; kc < 4; kc++) { bw[nt][kc] = cvt8(Wr + kc * 32 + quad * 8); pin(bw[nt][kc]); }
        }

        const int lrow = tid >> 4, lchunk = tid & 15;
        const int lb = lrow & 3, ltr = lrow >> 2;
        const float* xsrc = xin + (size_t)(p * 4 + lb) * T * 128 + lchunk * 8;

        for (int g = 0; g < NG; g++) {
            // lap-gate: don't overwrite xp slots the producer hasn't read.
            if (g >= 32 && tid == 0) {
                unsigned int need = (unsigned int)(8 * (g - 32));
                unsigned int psn = aldu32(pr);
                while (psn < need) { __builtin_amdgcn_s_sleep(4); psn = aldu32(pr); }
            }
            __syncthreads();
            {   // stage x granule, f32 -> f16
                f16x8 xv = cvt8(xsrc + (size_t)(g * 8 + ltr) * 128);
                u64p w2 = __builtin_bit_cast(u64p, xv);
                char* dst = (char*)&Ylh[lrow * YSTR + lchunk * 8];
                *(u64*)dst = w2.a;
                *(u64*)(dst + 8) = w2.b;
            }
            lds_barrier();

            float4v acc[2][4] = {};
#pragma unroll
            for (int kc = 0; kc < 4; kc++) {
                f16x8 y0 = *(const f16x8*)&Ylh[col * YSTR + kc * 32 + quad * 8];
                f16x8 y1t = *(const f16x8*)&Ylh[(16 + col) * YSTR + kc * 32 + quad * 8];
#pragma unroll
                for (int nt = 0; nt < 4; nt++) {
                    acc[0][nt] = __builtin_amdgcn_mfma_f32_16x16x32_f16(bw[nt][kc], y0,  acc[0][nt], 0, 0, 0);
                    acc[1][nt] = __builtin_amdgcn_mfma_f32_16x16x32_f16(bw[nt][kc], y1t, acc[1][nt], 0, 0, 0);
                }
            }
            {
                const int bb = col & 3;
#pragma unroll
                for (int mt = 0; mt < 2; mt++) {
                    int trow = mt * 4 + (col >> 2);
                    int slot = (g * 8 + trow) & (RING - 1);
                    _Float16* dst = X1 + ((size_t)(p * 4 + bb) * RING + slot) * 512 + (w * 4) * 16 + quad * 4;
#pragma unroll
                    for (int nt = 0; nt < 4; nt++)
                        ast64(dst + nt * 16, pack4(acc[mt][nt]));
                }
            }
            asm volatile("s_waitcnt vmcnt(0)" ::: "memory");
            __syncthreads();
            if (tid == 0) astu32(pr3, (unsigned int)(g * 8 + 8));
        }
    } else {
        // ========== out: d_out = y1 @ oW^T + ob; runs g = NG..2NG-1 =======
        f16x8 bo[4];
#pragma unroll
        for (int kc = 0; kc < 4; kc++) { bo[kc] = cvt8(oW + (size_t)(w * 16 + col) * 128 + kc * 32 + quad * 8); pin(bo[kc]); }
        float4v bv4 = *(const float4v*)(ob + w * 16 + quad * 4);

        const int lrow = tid >> 4, lchunk = tid & 15;
        const int lb = lrow & 3, ltr = lrow >> 2;

        for (int gg = 0; gg < NG; gg++) {
            const int g = NG + gg;
            if (tid == 0) {
                unsigned int need = (unsigned int)(g * 8 + 8);
                unsigned int psn = aldu32(pr4);
                while (psn < need) { __builtin_amdgcn_s_sleep(4); psn = aldu32(pr4); }
            }
            __syncthreads();   // also fences prior granule's Ylh reads
            {
                int slot = (g * 8 + ltr) & (RING - 1);
                const char* srcp = (const char*)(Y1 + ((size_t)(p * 4 + lb) * RING + slot) * 128 + lchunk * 8);
                u64 a0 = ald64(srcp);
                u64 a1 = ald64(srcp + 8);
                char* dst = (char*)&Ylh[lrow * YSTR + lchunk * 8];
                *(u64*)dst = a0;
                *(u64*)(dst + 8) = a1;
            }
            lds_barrier();
            // release consumed-progress: granule g's ring slots fully staged.
            if (tid == 0) astu32(pr5, (unsigned int)(g * 8 + 8));

            float4v acc[2] = {};
#pragma unroll
            for (int kc = 0; kc < 4; kc++) {
                f16x8 y0 = *(const f16x8*)&Ylh[col * YSTR + kc * 32 + quad * 8];
                f16x8 y1t = *(const f16x8*)&Ylh[(16 + col) * YSTR + kc * 32 + quad * 8];
                acc[0] = __builtin_amdgcn_mfma_f32_16x16x32_f16(bo[kc], y0,  acc[0], 0, 0, 0);
                acc[1] = __builtin_amdgcn_mfma_f32_16x16x32_f16(bo[kc], y1t, acc[1], 0, 0, 0);
            }
            {
                const int bb = col & 3;
#pragma unroll
                for (int mt = 0; mt < 2; mt++) {
                    int trow = mt * 4 + (col >> 2);
                    float4v v = acc[mt];
                    v[0] += bv4[0]; v[1] += bv4[1]; v[2] += bv4[2]; v[3] += bv4[3];
                    *(float4v*)(outp + ((size_t)(p * 4 + bb) * T + gg * 8 + trow) * 128 + w * 16 + quad * 4) = v;
                }
            }
        }
    }
}

// ---------------------------------------------------------------------------
// Host: memset + ONE launch.
//   ws map: X1 [0,16M) | X2 [16,32M) | PB [32,36M) | Y1 [36,40M) | prog @40M
// ---------------------------------------------------------------------------
extern "C" void kernel_launch(void* const* d_in, const int* in_sizes, int n_in,
                              void* d_out, int out_size, void* d_ws, size_t ws_size,
                              hipStream_t stream)
{
    const float* x    = (const float*)d_in[0];
    const float* eW0  = (const float*)d_in[1];
    const float* eU0  = (const float*)d_in[2];
    const float* eb0i = (const float*)d_in[3];
    const float* eb0h = (const float*)d_in[4];
    const float* eW1  = (const float*)d_in[5];
    const float* eU1  = (const float*)d_in[6];
    const float* eb1i = (const float*)d_in[7];
    const float* eb1h = (const float*)d_in[8];
    const float* dU0  = (const float*)d_in[10];
    const float* db0i = (const float*)d_in[11];
    const float* db0h = (const float*)d_in[12];
    const float* dW1  = (const float*)d_in[13];
    const float* dU1  = (const float*)d_in[14];
    const float* db1i = (const float*)d_in[15];
    const float* db1h = (const float*)d_in[16];
    const float* oW   = (const float*)d_in[17];
    const float* ob   = (const float*)d_in[18];

    char* ws = (char*)d_ws;
    _Float16* X1 = (_Float16*)(ws);                  // 16MB
    _Float16* X2 = (_Float16*)(ws + (16u << 20));    // 16MB
    _Float16* PB = (_Float16*)(ws + (32u << 20));    //  4MB
    _Float16* Y1 = (_Float16*)(ws + (36u << 20));    //  4MB
    unsigned int* pg = (unsigned int*)(ws + (40u << 20));

    // zero progress counters (graph-safe, re-zeroed every replay)
    hipMemsetAsync((void*)pg, 0, 8192, stream);

    lstm_mega<<<dim3(80), dim3(512), 0, stream>>>(
        eU0, eb0i, eb0h, dU0, db0i, db0h,
        eU1, eb1i, eb1h, dU1, db1i, db1h,
        eW1, dW1, eW0, x, oW, ob, (float*)d_out,
        PB, X2, X1, Y1,
        pg, pg + 256, pg + 512, pg + 768, pg + 1024, Tlen);
}